// Round 5
// baseline (163.813 us; speedup 1.0000x reference)
//
#include <hip/hip_runtime.h>

typedef unsigned short u16;
typedef __attribute__((ext_vector_type(4))) float f32x4;
typedef __attribute__((ext_vector_type(16))) float f32x16;
typedef __attribute__((ext_vector_type(8))) __bf16 bf16x8;
typedef __attribute__((ext_vector_type(2))) __bf16 bf16x2;

#define HEADS 32
#define KV_HEADS 8
#define HD 64
#define SEQ 2048
#define HID 2048
#define NQK 3072  // 2048 (Q) + 512 (K) + 512 (V)
#define QSCALE (0.125f * 1.4426950408889634f)  // exp2-domain softmax
#define OCH 2097152u  // u32s per partial-O chunk (512 blk * 4 waves * 16 * 64)

#define AS1 __attribute__((address_space(1)))
#define AS3 __attribute__((address_space(3)))

__device__ __forceinline__ u16 f2bf(float f) {
  unsigned u = __float_as_uint(f);
  u += 0x7FFFu + ((u >> 16) & 1u);
  return (u16)(u >> 16);
}

__device__ __forceinline__ unsigned pk2(float a, float b) {
  union { bf16x2 h; unsigned u; } c;
  c.h[0] = (__bf16)a; c.h[1] = (__bf16)b;
  return c.u;
}

__device__ __forceinline__ float bflo(unsigned u) {
  return __uint_as_float(u << 16);
}
__device__ __forceinline__ float bfhi(unsigned u) {
  return __uint_as_float(u & 0xFFFF0000u);
}

__device__ __forceinline__ void load16_to_lds(const void* g, void* l) {
  __builtin_amdgcn_global_load_lds((AS1 void*)(void*)g, (AS3 void*)l, 16, 0, 0);
}

// ---------- fp32 -> bf16 elementwise (4 elems/thread) ----------
__global__ __launch_bounds__(256) void k_f2b(const float* __restrict__ in,
                                             u16* __restrict__ out, int n4) {
  int i = blockIdx.x * 256 + threadIdx.x;
  if (i >= n4) return;
  float4 v = ((const float4*)in)[i];
  ushort4 o;
  o.x = f2bf(v.x); o.y = f2bf(v.y); o.z = f2bf(v.z); o.w = f2bf(v.w);
  ((ushort4*)out)[i] = o;
}

// ---------- transpose + convert: out[c*ldo + r] = bf16(in[r*ldi + c]) ----------
__global__ __launch_bounds__(256) void k_tconv(const float* __restrict__ in, int ldi,
                                               u16* __restrict__ out, int ldo) {
  __shared__ float tile[32][33];
  int c0 = blockIdx.x * 32, r0 = blockIdx.y * 32;
  int col = threadIdx.x & 31, rw = threadIdx.x >> 5;
#pragma unroll
  for (int i = 0; i < 4; i++)
    tile[rw + i * 8][col] = in[(size_t)(r0 + rw + i * 8) * ldi + c0 + col];
  __syncthreads();
#pragma unroll
  for (int i = 0; i < 4; i++)
    out[(size_t)(c0 + rw + i * 8) * ldo + r0 + col] = f2bf(tile[col][rw + i * 8]);
}

// ======================= out-proj GEMM (R3 template, verbatim) ==============
// 128x128 block tile, BK=64, 4 waves each 64x64 quadrant, depth-2 counted
// vmcnt pipeline, 8-slot source-swizzle (measured conflict-free in R3).

__device__ __forceinline__ void stage8(const u16* Ap, const u16* Bp, u16* AsX,
                                       u16* BsX, int tid, int K, int koff) {
#pragma unroll
  for (int i = 0; i < 4; i++) {
    load16_to_lds(Ap + (size_t)(i * 32) * K + koff, AsX + (i * 256 + tid) * 8);
    load16_to_lds(Bp + (size_t)(i * 32) * K + koff, BsX + (i * 256 + tid) * 8);
  }
}

__device__ __forceinline__ void frag16(const u16* Asb, const u16* Bsb,
                                       const int aoff[4][2], const int boff[4][2],
                                       f32x4 acc[4][4]) {
#pragma unroll
  for (int kk = 0; kk < 2; kk++) {
    bf16x8 a[4], b[4];
#pragma unroll
    for (int i = 0; i < 4; i++)
      a[i] = *(const bf16x8*)((const char*)Asb + aoff[i][kk]);
#pragma unroll
    for (int j = 0; j < 4; j++)
      b[j] = *(const bf16x8*)((const char*)Bsb + boff[j][kk]);
#pragma unroll
    for (int i = 0; i < 4; i++)
#pragma unroll
      for (int j = 0; j < 4; j++)
        acc[i][j] = __builtin_amdgcn_mfma_f32_16x16x32_bf16(a[i], b[j], acc[i][j], 0, 0, 0);
  }
}

#define TILE_STEP(AsX, BsX, tnext)                              \
  do {                                                          \
    asm volatile("s_waitcnt vmcnt(8)" ::: "memory");            \
    __builtin_amdgcn_sched_barrier(0);                          \
    __builtin_amdgcn_s_barrier();                               \
    frag16(AsX, BsX, aoff, boff, acc);                          \
    __builtin_amdgcn_sched_barrier(0);                          \
    __builtin_amdgcn_s_barrier();                               \
    stage8(Ap, Bp, AsX, BsX, tid, K, (tnext) * 64);             \
    __builtin_amdgcn_sched_barrier(0);                          \
  } while (0)

#define TILE_TAIL(AsX, BsX, n)                                  \
  do {                                                          \
    asm volatile("s_waitcnt vmcnt(" #n ")" ::: "memory");       \
    __builtin_amdgcn_sched_barrier(0);                          \
    __builtin_amdgcn_s_barrier();                               \
    frag16(AsX, BsX, aoff, boff, acc);                          \
  } while (0)

__global__ __launch_bounds__(256) void k_gemm(const u16* __restrict__ A,
                                              const u16* __restrict__ Bt,
                                              float* __restrict__ C,
                                              int M, int N, int K) {
  __shared__ u16 smem[32768];  // 64KB: 2 x (A 16KB + B 16KB)
  u16* As0 = smem;          u16* As1 = smem + 8192;
  u16* Bs0 = smem + 16384;  u16* Bs1 = smem + 24576;
  int tid = threadIdx.x;
  int m0 = blockIdx.x * 128, n0 = blockIdx.y * 128;
  int l = tid & 63, w = tid >> 6;
  int lr = l & 15, lg = l >> 4;
  int wr = (w >> 1) * 64, wc = (w & 1) * 64;
  f32x4 acc[4][4] = {};
  int r8 = tid >> 3;
  int sx = (tid & 7) ^ (r8 & 7);
  const u16* Ap = A + (size_t)(m0 + r8) * K + sx * 8;
  const u16* Bp = Bt + (size_t)(n0 + r8) * K + sx * 8;
  int aoff[4][2], boff[4][2];
#pragma unroll
  for (int i = 0; i < 4; i++) {
    int ra = wr + i * 16 + lr;
    int rb = wc + i * 16 + lr;
#pragma unroll
    for (int kk = 0; kk < 2; kk++) {
      aoff[i][kk] = ra * 128 + (((lg + kk * 4) ^ (ra & 7)) << 4);
      boff[i][kk] = rb * 128 + (((lg + kk * 4) ^ (rb & 7)) << 4);
    }
  }
  stage8(Ap, Bp, As0, Bs0, tid, K, 0);
  stage8(Ap, Bp, As1, Bs1, tid, K, 64);
#pragma unroll 1
  for (int t = 0; t < 30; t += 2) {
    TILE_STEP(As0, Bs0, t + 2);
    TILE_STEP(As1, Bs1, t + 3);
  }
  TILE_TAIL(As0, Bs0, 8);
  TILE_TAIL(As1, Bs1, 0);

#pragma unroll
  for (int i = 0; i < 4; i++)
#pragma unroll
    for (int j = 0; j < 4; j++)
#pragma unroll
      for (int r = 0; r < 4; r++)
        C[(size_t)(m0 + wr + i * 16 + lg * 4 + r) * N + n0 + wc + j * 16 + lr] =
            acc[i][j][r];
}

// ======================= QKV GEMM (R5: B direct global->reg) ================
// 128x128 tile, BK=64, 4 waves.  A staged via global_load_lds (8-slot swizzle,
// depth-2, 32KB LDS).  B: 8 bf16x8 fragments per wave per tile loaded DIRECTLY
// global->registers (L2-resident weights; one lg-quad covers a full 64B line),
// double-buffered in named regs one tile ahead — halves LDS traffic and drops
// 2/3 of the gload_lds DMA writes.  One barrier/tile; manual vmcnt(8) covers
// only A; compiler inserts exact waits for the B register loads.
// Per-iter issue order keeps the queue invariant [A(t)x4, B(t)x8] at entry.

__device__ __forceinline__ void stageA4(const u16* Ap, u16* AsX, int tid, int K,
                                        int koff) {
#pragma unroll
  for (int i = 0; i < 4; i++)
    load16_to_lds(Ap + (size_t)(i * 32) * K + koff, AsX + (i * 256 + tid) * 8);
}

#define QKV_LOADB(BQ, kt)                                                     \
  _Pragma("unroll") for (int j = 0; j < 4; j++)                               \
  _Pragma("unroll") for (int kk = 0; kk < 2; kk++)                            \
      BQ[j * 2 + kk] =                                                        \
          *(const bf16x8*)(Bgl + (size_t)(j * 16) * K + (kt) * 64 + kk * 32);

#define QKV_COMP(AsR, BQ)                                                     \
  {                                                                           \
    bf16x8 a_[4][2];                                                          \
    _Pragma("unroll") for (int i = 0; i < 4; i++)                             \
    _Pragma("unroll") for (int kk = 0; kk < 2; kk++)                          \
        a_[i][kk] = *(const bf16x8*)((const char*)(AsR) + aoff[i][kk]);       \
    __builtin_amdgcn_s_setprio(1);                                            \
    _Pragma("unroll") for (int kk = 0; kk < 2; kk++)                          \
    _Pragma("unroll") for (int i = 0; i < 4; i++)                             \
    _Pragma("unroll") for (int j = 0; j < 4; j++)                             \
        acc[i][j] = __builtin_amdgcn_mfma_f32_16x16x32_bf16(                  \
            a_[i][kk], BQ[j * 2 + kk], acc[i][j], 0, 0, 0);                   \
    __builtin_amdgcn_s_setprio(0);                                            \
  }

#define QKV_IT(AsR, AsW, BQc, BQn, tnext)                                     \
  do {                                                                        \
    asm volatile("s_waitcnt vmcnt(8)" ::: "memory");                          \
    __builtin_amdgcn_sched_barrier(0);                                        \
    __builtin_amdgcn_s_barrier();                                             \
    stageA4(Ap, AsW, tid, K, (tnext) * 64);                                   \
    __builtin_amdgcn_sched_barrier(0);                                        \
    QKV_COMP(AsR, BQc)                                                        \
    QKV_LOADB(BQn, tnext)                                                     \
    __builtin_amdgcn_sched_barrier(0);                                        \
  } while (0)

__global__ __launch_bounds__(256) void k_gemm_qkv(const u16* __restrict__ A,
                                                  const u16* __restrict__ Bt,
                                                  const float* __restrict__ cosp,
                                                  const float* __restrict__ sinp,
                                                  u16* __restrict__ qbuf,
                                                  u16* __restrict__ kbuf,
                                                  u16* __restrict__ vtb) {
  __shared__ u16 smem[16384];  // 32KB: 2 x A 16KB; V-transpose Ts aliases all
  u16* As0 = smem;
  u16* As1 = smem + 8192;
  u16* Ts = smem;
  const int K = HID;
  int tid = threadIdx.x;
  int m0 = blockIdx.x * 128, n0 = blockIdx.y * 128;
  int l = tid & 63, w = tid >> 6;
  int lr = l & 15, lg = l >> 4;
  int wr = (w >> 1) * 64, wc = (w & 1) * 64;
  f32x4 acc[4][4] = {};
  int r8 = tid >> 3;
  int sx = (tid & 7) ^ (r8 & 7);
  const u16* Ap = A + (size_t)(m0 + r8) * K + sx * 8;
  const u16* Bgl = Bt + (size_t)(n0 + wc + lr) * K + lg * 8;
  int aoff[4][2];
#pragma unroll
  for (int i = 0; i < 4; i++) {
    int ra = wr + i * 16 + lr;
#pragma unroll
    for (int kk = 0; kk < 2; kk++)
      aoff[i][kk] = ra * 128 + (((lg + kk * 4) ^ (ra & 7)) << 4);
  }

  bf16x8 bq0[8], bq1[8];
  stageA4(Ap, As0, tid, K, 0);
  QKV_LOADB(bq0, 0)
#pragma unroll 1
  for (int t = 0; t < 30; t += 2) {
    QKV_IT(As0, As1, bq0, bq1, t + 1);
    QKV_IT(As1, As0, bq1, bq0, t + 2);
  }
  QKV_IT(As0, As1, bq0, bq1, 31);  // t=30
  // t=31 tail: nothing left to issue
  asm volatile("s_waitcnt vmcnt(8)" ::: "memory");
  __builtin_amdgcn_sched_barrier(0);
  __builtin_amdgcn_s_barrier();
  QKV_COMP(As1, bq1)

  if (n0 < 2560) {
    // ---- Q or K: fused RoPE, direct bf16 stores (head-major) ----
    int colbase = n0 + wc;
    bool isQ = colbase < 2048;
    float scale = isQ ? QSCALE : 1.0f;
    u16* base = isQ ? qbuf + (size_t)(colbase >> 6) * SEQ * HD
                    : kbuf + (size_t)((colbase - 2048) >> 6) * SEQ * HD;
    int odd = lr & 1;
#pragma unroll
    for (int i = 0; i < 4; i++)
#pragma unroll
      for (int j = 0; j < 4; j++) {
        int ii = j * 8 + (lr >> 1);
#pragma unroll
        for (int r = 0; r < 4; r++) {
          float v = acc[i][j][r];
          float vp = __shfl_xor(v, 1, 64);
          int sr = m0 + wr + i * 16 + lg * 4 + r;
          float cs = cosp[sr * 32 + ii], sn = sinp[sr * 32 + ii];
          float x1 = odd ? vp : v, x2 = odd ? v : vp;
          float o = odd ? (x1 * sn + x2 * cs) : (x1 * cs - x2 * sn);
          base[(size_t)sr * HD + j * 16 + lr] = f2bf(o * scale);
        }
      }
  } else {
    // ---- V: LDS transpose -> coalesced vtb writes (Ts aliases pipe bufs) ----
    __syncthreads();  // all waves done reading pipeline buffers
#pragma unroll
    for (int i = 0; i < 4; i++)
#pragma unroll
      for (int j = 0; j < 4; j++)
#pragma unroll
        for (int r = 0; r < 4; r++) {
          int cB = wc + j * 16 + lr, rB = wr + i * 16 + lg * 4 + r;
          *(u16*)((char*)Ts + cB * 256 + ((rB * 2) ^ ((cB & 7) << 4))) =
              f2bf(acc[i][j][r]);
        }
    __syncthreads();
    int c = tid >> 1, half = tid & 1;
    int col = n0 + c;
    int kvh = (col - 2560) >> 6, d = col & 63;
    u16* dst = vtb + (size_t)kvh * HD * SEQ + (size_t)d * SEQ + m0 + half * 64;
    const char* src = (const char*)Ts + c * 256;
    int cs7 = (c & 7) << 4;
#pragma unroll
    for (int q = 0; q < 8; q++)
      *(uint4*)(dst + q * 8) = *(const uint4*)(src + ((half * 128 + q * 16) ^ cs7));
  }
}

// ---------- Flash attention pass 1: KV-split x2, partial O + (m,l) ----------
__global__ __launch_bounds__(256) void k_flash2(const u16* __restrict__ qb,
                                                const u16* __restrict__ kb,
                                                const u16* __restrict__ vt,
                                                unsigned* __restrict__ Opart,
                                                float2* __restrict__ ml) {
  __shared__ u16 Ks[2][64 * 64];
  __shared__ u16 Vs[2][64 * 64];
  int bid = blockIdx.x;
  int c = bid & 1;                  // chunk fastest
  int b5 = bid >> 1;                // 0..511
  int h = b5 & 31;                  // heads next
  int qi = b5 >> 5;
  int qblk = (SEQ / 128) - 1 - qi;  // LPT: heaviest first
  int kvh = h & 7;
  int tid = threadIdx.x, w = tid >> 6, l = tid & 63;
  int lq = l & 31, hi = l >> 5;
  const u16* qh = qb + (size_t)h * SEQ * HD;
  const u16* kh = kb + (size_t)kvh * SEQ * HD;
  const u16* vh = vt + (size_t)kvh * HD * SEQ;
  int wq0 = qblk * 128 + w * 32;
  int qg = wq0 + lq;

  bf16x8 qf[4];
#pragma unroll
  for (int ds = 0; ds < 4; ds++)
    qf[ds] = *(const bf16x8*)(qh + (size_t)qg * HD + ds * 16 + hi * 8);

  f32x16 acc[2] = {};   // O^T: lane: q=l&31, d = dt*32 + (r&3)+8*(r>>2)+4*hi
  float m_r = -__builtin_inff(), l_r = 0.f;

  int srow = tid >> 2, c4 = tid & 3, swz = (srow & 7) << 4;
  int sd0 = srow * 128 + ((c4 * 32) ^ swz);
  int sd1 = srow * 128 + ((c4 * 32 + 16) ^ swz);
  const int kt0 = c * (qblk + 1), kt1 = kt0 + qblk + 1;

  // prologue: stage tile kt0
  {
    const u16* ksrc = kh + (size_t)(kt0 * 64 + srow) * HD + c4 * 16;
    const u16* vsrc = vh + (size_t)srow * SEQ + kt0 * 64 + c4 * 16;
    uint4 a0 = *(const uint4*)(ksrc), a1 = *(const uint4*)(ksrc + 8);
    uint4 b0 = *(const uint4*)(vsrc), b1 = *(const uint4*)(vsrc + 8);
    *(uint4*)((char*)Ks[0] + sd0) = a0; *(uint4*)((char*)Ks[0] + sd1) = a1;
    *(uint4*)((char*)Vs[0] + sd0) = b0; *(uint4*)((char*)Vs[0] + sd1) = b1;
  }
  __syncthreads();

  uint4 kr0, kr1, vr0, vr1;
  int lswz = (lq & 7) << 4;
  for (int kt = kt0; kt < kt1; kt++) {
    int b = (kt - kt0) & 1;
    if (kt + 1 < kt1) {
      const u16* ksrc = kh + (size_t)((kt + 1) * 64 + srow) * HD + c4 * 16;
      const u16* vsrc = vh + (size_t)srow * SEQ + (kt + 1) * 64 + c4 * 16;
      kr0 = *(const uint4*)(ksrc); kr1 = *(const uint4*)(ksrc + 8);
      vr0 = *(const uint4*)(vsrc); vr1 = *(const uint4*)(vsrc + 8);
    }

    if (kt * 64 <= wq0 + 31) {  // skip fully-masked tiles
      f32x16 sT[2] = {};
      const char* kbase = (const char*)Ks[b];
      __builtin_amdgcn_s_setprio(1);
#pragma unroll
      for (int t = 0; t < 2; t++) {
#pragma unroll
        for (int ds = 0; ds < 4; ds++) {
          bf16x8 kf = *(const bf16x8*)(kbase + (t * 32 + lq) * 128 +
                                       ((ds * 32 + hi * 16) ^ lswz));
          sT[t] = __builtin_amdgcn_mfma_f32_32x32x16_bf16(kf, qf[ds], sT[t], 0, 0, 0);
        }
      }
      __builtin_amdgcn_s_setprio(0);

      if (kt * 64 + 63 > wq0) {
#pragma unroll
        for (int t = 0; t < 2; t++)
#pragma unroll
          for (int r = 0; r < 16; r++) {
            int kg = kt * 64 + t * 32 + (r & 3) + 8 * (r >> 2) + 4 * hi;
            if (kg > qg) sT[t][r] = -__builtin_inff();
          }
      }

      float pmax = sT[0][0];
#pragma unroll
      for (int r = 1; r < 16; r++) pmax = fmaxf(pmax, sT[0][r]);
#pragma unroll
      for (int r = 0; r < 16; r++) pmax = fmaxf(pmax, sT[1][r]);
      pmax = fmaxf(pmax, __shfl_xor(pmax, 32, 64));

      if (!__all(pmax <= m_r + 8.f)) {
        float mn = fmaxf(m_r, pmax);
        float scl = __builtin_amdgcn_exp2f(m_r - mn);
        l_r *= scl;
        acc[0] *= scl;
        acc[1] *= scl;
        m_r = mn;
      }

      float ss = 0.f;
#pragma unroll
      for (int t = 0; t < 2; t++)
#pragma unroll
        for (int r = 0; r < 16; r++) {
          float p = __builtin_amdgcn_exp2f(sT[t][r] - m_r);
          sT[t][r] = p;
          ss += p;
        }
      ss += __shfl_xor(ss, 32, 64);
      l_r += ss;

      const char* vbase = (const char*)Vs[b];
#pragma unroll
      for (int t = 0; t < 2; t++) {
        unsigned cp[4][2];
#pragma unroll
        for (int m = 0; m < 4; m++) {
          cp[m][0] = pk2(sT[t][4 * m + 0], sT[t][4 * m + 1]);
          cp[m][1] = pk2(sT[t][4 * m + 2], sT[t][4 * m + 3]);
        }
#pragma unroll
        for (int kl = 0; kl < 2; kl++) {
          unsigned s0 = hi ? cp[2 * kl][0] : cp[2 * kl + 1][0];
          unsigned s1 = hi ? cp[2 * kl][1] : cp[2 * kl + 1][1];
          unsigned r0 = (unsigned)__shfl_xor((int)s0, 32, 64);
          unsigned r1 = (unsigned)__shfl_xor((int)s1, 32, 64);
          union { unsigned u[4]; bf16x8 v; } pa;
          pa.u[0] = hi ? r0 : cp[2 * kl][0];
          pa.u[1] = hi ? r1 : cp[2 * kl][1];
          pa.u[2] = hi ? cp[2 * kl + 1][0] : r0;
          pa.u[3] = hi ? cp[2 * kl + 1][1] : r1;
          int ks = t * 2 + kl;
          __builtin_amdgcn_s_setprio(1);
#pragma unroll
          for (int dt = 0; dt < 2; dt++) {
            bf16x8 vb = *(const bf16x8*)(vbase + (dt * 32 + lq) * 128 +
                                         ((ks * 32 + hi * 16) ^ lswz));
            acc[dt] = __builtin_amdgcn_mfma_f32_32x32x16_bf16(vb, pa.v, acc[dt], 0, 0, 0);
          }
          __builtin_amdgcn_s_setprio(0);
        }
      }
    }

    if (kt + 1 < kt1) {
      *(uint4*)((char*)Ks[b ^ 1] + sd0) = kr0;
      *(uint4*)((char*)Ks[b ^ 1] + sd1) = kr1;
      *(uint4*)((char*)Vs[b ^ 1] + sd0) = vr0;
      *(uint4*)((char*)Vs[b ^ 1] + sd1) = vr1;
    }
    __syncthreads();
  }

  // epilogue: dump raw-lane-layout partial O (bf16 pairs) + (m,l), coalesced
  unsigned* op = Opart + (size_t)c * OCH + ((size_t)(b5 * 4 + w) * 16) * 64;
#pragma unroll
  for (int dt = 0; dt < 2; dt++)
#pragma unroll
    for (int j = 0; j < 8; j++)
      op[(dt * 8 + j) * 64 + l] = pk2(acc[dt][2 * j], acc[dt][2 * j + 1]);
  if (!hi)
    ml[c * (HEADS * SEQ) + h * SEQ + wq0 + lq] = make_float2(m_r, l_r);
}

// ---------- Flash pass 2: merge chunk partials, transpose, write av ----------
__global__ __launch_bounds__(256) void k_merge(const unsigned* __restrict__ Opart,
                                               const float2* __restrict__ ml,
                                               u16* __restrict__ av) {
  __shared__ u16 Ts[8192];  // 16KB: 4 waves x 4KB transpose staging
  int bid = blockIdx.x;
  int h = bid & 31, qblk = bid >> 5;
  int b5 = ((SEQ / 128 - 1 - qblk) << 5) | h;  // pass-1 flat block index
  int tid = threadIdx.x, w = tid >> 6, l = tid & 63;
  int lq = l & 31, hi = l >> 5;
  int wq0 = qblk * 128 + w * 32;

  float2 ml0 = ml[h * SEQ + wq0 + lq];
  float2 ml1 = ml[HEADS * SEQ + h * SEQ + wq0 + lq];
  float m = fmaxf(ml0.x, ml1.x);
  float f0 = __builtin_amdgcn_exp2f(ml0.x - m);
  float f1 = __builtin_amdgcn_exp2f(ml1.x - m);
  float inv = 1.0f / (ml0.y * f0 + ml1.y * f1);

  const unsigned* op0 = Opart + ((size_t)(b5 * 4 + w) * 16) * 64;
  const unsigned* op1 = op0 + OCH;
  f32x16 acc[2];
#pragma unroll
  for (int dt = 0; dt < 2; dt++)
#pragma unroll
    for (int j = 0; j < 8; j++) {
      unsigned a0 = op0[(dt * 8 + j) * 64 + l];
      unsigned a1 = op1[(dt * 8 + j) * 64 + l];
      acc[dt][2 * j] = bflo(a0) * f0 + bflo(a1) * f1;
      acc[dt][2 * j + 1] = bfhi(a0) * f0 + bfhi(a1) * f1;
    }

  // LDS transpose epilogue (identical to R6 flash)
  int lswz = (lq & 7) << 4;
  char* wbase = (char*)Ts + w * 4096;
#pragma unroll
  for (int dt = 0; dt < 2; dt++)
#pragma unroll
    for (int m4 = 0; m4 < 4; m4++) {
      int r0 = 4 * m4;
      uint2 pr;
      pr.x = pk2(acc[dt][r0 + 0] * inv, acc[dt][r0 + 1] * inv);
      pr.y = pk2(acc[dt][r0 + 2] * inv, acc[dt][r0 + 3] * inv);
      int byte = lq * 128 + ((dt * 64 + m4 * 16 + hi * 8) ^ lswz);
      *(uint2*)(wbase + byte) = pr;
    }
  __syncthreads();
  int q2 = l >> 1, cH = l & 1;
  int qswz = (q2 & 7) << 4;
#pragma unroll
  for (int i = 0; i < 4; i++) {
    uint4 d = *(const uint4*)(wbase + q2 * 128 + ((cH * 64 + i * 16) ^ qswz));
    *(uint4*)(av + (size_t)(wq0 + q2) * HID + h * HD + cH * 32 + i * 8) = d;
  }
}

extern "C" void kernel_launch(void* const* d_in, const int* in_sizes, int n_in,
                              void* d_out, int out_size, void* d_ws, size_t ws_size,
                              hipStream_t stream) {
  (void)in_sizes; (void)n_in; (void)out_size; (void)ws_size;
  const float* x = (const float*)d_in[0];
  const float* cosp = (const float*)d_in[1];
  const float* sinp = (const float*)d_in[2];
  const float* Wq = (const float*)d_in[3];
  const float* Wk = (const float*)d_in[4];
  const float* Wv = (const float*)d_in[5];
  const float* Wo = (const float*)d_in[6];
  float* out = (float*)d_out;
  char* ws = (char*)d_ws;

  // workspace layout (64 MiB exactly):
  u16* xb = (u16*)(ws);                          // [0,8M)   x bf16; dead after qkv
  float2* mlb = (float2*)(ws);                   // [0,1M)   aliases dead xb (flash2+)
  u16* Wqkv = (u16*)(ws + ((size_t)8 << 20));    // [8,20M)  Wq^T|Wk^T|Wv^T
  u16* WoT = (u16*)(ws + ((size_t)20 << 20));    // [20,28M) Wo^T
  u16* qbuf = (u16*)(ws + ((size_t)28 << 20));   // [28,36M) q rope bf16 [32][S][64]
  u16* kbuf = (u16*)(ws + ((size_t)36 << 20));   // [36,38M) k rope bf16 [8][S][64]
  u16* vtb = (u16*)(ws + ((size_t)38 << 20));    // [38,40M) v^T bf16 [8][64][S]
  u16* av = (u16*)(ws + ((size_t)40 << 20));     // [40,48M) av bf16 [S][2048]
  unsigned* Opart = (unsigned*)(ws + ((size_t)48 << 20));  // [48,64M) 2 chunks x 8M

  k_f2b<<<(SEQ * HID / 4 + 255) / 256, 256, 0, stream>>>(x, xb, SEQ * HID / 4);
  k_tconv<<<dim3(HID / 32, HID / 32), 256, 0, stream>>>(Wq, HID, Wqkv, HID);
  k_tconv<<<dim3(512 / 32, HID / 32), 256, 0, stream>>>(Wk, 512, Wqkv + (size_t)2048 * HID, HID);
  k_tconv<<<dim3(512 / 32, HID / 32), 256, 0, stream>>>(Wv, 512, Wqkv + (size_t)2560 * HID, HID);
  k_tconv<<<dim3(HID / 32, HID / 32), 256, 0, stream>>>(Wo, HID, WoT, HID);
  k_gemm_qkv<<<dim3(SEQ / 128, NQK / 128), 256, 0, stream>>>(xb, Wqkv, cosp, sinp,
                                                             qbuf, kbuf, vtb);
  k_flash2<<<(SEQ / 128) * HEADS * 2, 256, 0, stream>>>(qbuf, kbuf, vtb, Opart, mlb);
  k_merge<<<(SEQ / 128) * HEADS, 256, 0, stream>>>(Opart, mlb, av);
  k_gemm<<<dim3(SEQ / 128, HID / 128), 256, 0, stream>>>(av, WoT, out, SEQ, HID, HID);
}

// Round 6
// 129.399 us; speedup vs baseline: 1.2660x; 1.2660x over previous
//
#include <hip/hip_runtime.h>

typedef unsigned short u16;
typedef __attribute__((ext_vector_type(4))) float f32x4;
typedef __attribute__((ext_vector_type(16))) float f32x16;
typedef __attribute__((ext_vector_type(8))) __bf16 bf16x8;
typedef __attribute__((ext_vector_type(2))) __bf16 bf16x2;

#define HEADS 32
#define KV_HEADS 8
#define HD 64
#define SEQ 2048
#define HID 2048
#define NQK 3072  // 2048 (Q) + 512 (K) + 512 (V)
#define QSCALE (0.125f * 1.4426950408889634f)  // exp2-domain softmax
#define OCH 2097152u  // u32s per partial-O chunk (512 blk * 4 waves * 16 * 64)

#define AS1 __attribute__((address_space(1)))
#define AS3 __attribute__((address_space(3)))

__device__ __forceinline__ u16 f2bf(float f) {
  unsigned u = __float_as_uint(f);
  u += 0x7FFFu + ((u >> 16) & 1u);
  return (u16)(u >> 16);
}

__device__ __forceinline__ unsigned pk2(float a, float b) {
  union { bf16x2 h; unsigned u; } c;
  c.h[0] = (__bf16)a; c.h[1] = (__bf16)b;
  return c.u;
}

__device__ __forceinline__ float bflo(unsigned u) {
  return __uint_as_float(u << 16);
}
__device__ __forceinline__ float bfhi(unsigned u) {
  return __uint_as_float(u & 0xFFFF0000u);
}

__device__ __forceinline__ void load16_to_lds(const void* g, void* l) {
  __builtin_amdgcn_global_load_lds((AS1 void*)(void*)g, (AS3 void*)l, 16, 0, 0);
}

// ---------- fp32 -> bf16 elementwise (4 elems/thread) ----------
__global__ __launch_bounds__(256) void k_f2b(const float* __restrict__ in,
                                             u16* __restrict__ out, int n4) {
  int i = blockIdx.x * 256 + threadIdx.x;
  if (i >= n4) return;
  float4 v = ((const float4*)in)[i];
  ushort4 o;
  o.x = f2bf(v.x); o.y = f2bf(v.y); o.z = f2bf(v.z); o.w = f2bf(v.w);
  ((ushort4*)out)[i] = o;
}

// ---------- transpose + convert: out[c*ldo + r] = bf16(in[r*ldi + c]) ----------
__global__ __launch_bounds__(256) void k_tconv(const float* __restrict__ in, int ldi,
                                               u16* __restrict__ out, int ldo) {
  __shared__ float tile[32][33];
  int c0 = blockIdx.x * 32, r0 = blockIdx.y * 32;
  int col = threadIdx.x & 31, rw = threadIdx.x >> 5;
#pragma unroll
  for (int i = 0; i < 4; i++)
    tile[rw + i * 8][col] = in[(size_t)(r0 + rw + i * 8) * ldi + c0 + col];
  __syncthreads();
#pragma unroll
  for (int i = 0; i < 4; i++)
    out[(size_t)(c0 + rw + i * 8) * ldo + r0 + col] = f2bf(tile[col][rw + i * 8]);
}

// ======================= out-proj GEMM (R3 template, verbatim) ==============
// 128x128 block tile, BK=64, 4 waves each 64x64 quadrant, depth-2 counted
// vmcnt pipeline, 8-slot source-swizzle (measured conflict-free in R3).
// Grid 16x16 = 256 = exactly 1 block/CU; measured ~860 TF equiv.

__device__ __forceinline__ void stage8(const u16* Ap, const u16* Bp, u16* AsX,
                                       u16* BsX, int tid, int K, int koff) {
#pragma unroll
  for (int i = 0; i < 4; i++) {
    load16_to_lds(Ap + (size_t)(i * 32) * K + koff, AsX + (i * 256 + tid) * 8);
    load16_to_lds(Bp + (size_t)(i * 32) * K + koff, BsX + (i * 256 + tid) * 8);
  }
}

__device__ __forceinline__ void frag16(const u16* Asb, const u16* Bsb,
                                       const int aoff[4][2], const int boff[4][2],
                                       f32x4 acc[4][4]) {
#pragma unroll
  for (int kk = 0; kk < 2; kk++) {
    bf16x8 a[4], b[4];
#pragma unroll
    for (int i = 0; i < 4; i++)
      a[i] = *(const bf16x8*)((const char*)Asb + aoff[i][kk]);
#pragma unroll
    for (int j = 0; j < 4; j++)
      b[j] = *(const bf16x8*)((const char*)Bsb + boff[j][kk]);
#pragma unroll
    for (int i = 0; i < 4; i++)
#pragma unroll
      for (int j = 0; j < 4; j++)
        acc[i][j] = __builtin_amdgcn_mfma_f32_16x16x32_bf16(a[i], b[j], acc[i][j], 0, 0, 0);
  }
}

#define TILE_STEP(AsX, BsX, tnext)                              \
  do {                                                          \
    asm volatile("s_waitcnt vmcnt(8)" ::: "memory");            \
    __builtin_amdgcn_sched_barrier(0);                          \
    __builtin_amdgcn_s_barrier();                               \
    frag16(AsX, BsX, aoff, boff, acc);                          \
    __builtin_amdgcn_sched_barrier(0);                          \
    __builtin_amdgcn_s_barrier();                               \
    stage8(Ap, Bp, AsX, BsX, tid, K, (tnext) * 64);             \
    __builtin_amdgcn_sched_barrier(0);                          \
  } while (0)

#define TILE_TAIL(AsX, BsX, n)                                  \
  do {                                                          \
    asm volatile("s_waitcnt vmcnt(" #n ")" ::: "memory");       \
    __builtin_amdgcn_sched_barrier(0);                          \
    __builtin_amdgcn_s_barrier();                               \
    frag16(AsX, BsX, aoff, boff, acc);                          \
  } while (0)

__global__ __launch_bounds__(256) void k_gemm(const u16* __restrict__ A,
                                              const u16* __restrict__ Bt,
                                              float* __restrict__ C,
                                              int M, int N, int K) {
  __shared__ u16 smem[32768];  // 64KB: 2 x (A 16KB + B 16KB)
  u16* As0 = smem;          u16* As1 = smem + 8192;
  u16* Bs0 = smem + 16384;  u16* Bs1 = smem + 24576;
  int tid = threadIdx.x;
  int m0 = blockIdx.x * 128, n0 = blockIdx.y * 128;
  int l = tid & 63, w = tid >> 6;
  int lr = l & 15, lg = l >> 4;
  int wr = (w >> 1) * 64, wc = (w & 1) * 64;
  f32x4 acc[4][4] = {};
  int r8 = tid >> 3;
  int sx = (tid & 7) ^ (r8 & 7);
  const u16* Ap = A + (size_t)(m0 + r8) * K + sx * 8;
  const u16* Bp = Bt + (size_t)(n0 + r8) * K + sx * 8;
  int aoff[4][2], boff[4][2];
#pragma unroll
  for (int i = 0; i < 4; i++) {
    int ra = wr + i * 16 + lr;
    int rb = wc + i * 16 + lr;
#pragma unroll
    for (int kk = 0; kk < 2; kk++) {
      aoff[i][kk] = ra * 128 + (((lg + kk * 4) ^ (ra & 7)) << 4);
      boff[i][kk] = rb * 128 + (((lg + kk * 4) ^ (rb & 7)) << 4);
    }
  }
  stage8(Ap, Bp, As0, Bs0, tid, K, 0);
  stage8(Ap, Bp, As1, Bs1, tid, K, 64);
#pragma unroll 1
  for (int t = 0; t < 30; t += 2) {
    TILE_STEP(As0, Bs0, t + 2);
    TILE_STEP(As1, Bs1, t + 3);
  }
  TILE_TAIL(As0, Bs0, 8);
  TILE_TAIL(As1, Bs1, 0);

#pragma unroll
  for (int i = 0; i < 4; i++)
#pragma unroll
    for (int j = 0; j < 4; j++)
#pragma unroll
      for (int r = 0; r < 4; r++)
        C[(size_t)(m0 + wr + i * 16 + lg * 4 + r) * N + n0 + wc + j * 16 + lr] =
            acc[i][j][r];
}

// ======================= QKV GEMM (R6: 128x192 tile, grid 256) ==============
// BM=128 x BN=192 -> grid 16x16 = 256 blocks = exactly 1/CU (R3-R4 ran 384 =
// 1.5/CU; makespan was set by the 2-block CUs at 75% utilization).  Same R3
// pipeline: depth-2, global_load_lds with 8-slot source swizzle (slot s of
// row r holds global segment s^(r&7); swizzle applied on global src addr,
// inverted identically on ds_read).  10 loads/thread/tile (A:4, B:6) ->
// steady-state vmcnt(10).  LDS 80KB.  Wave tile 64x96 (4x6 frags, 48 MFMA).
// Bijective XCD swizzle: lin%8 = XCD gets 2 contiguous B-panels (L2 reuse).
// Epilogue classifies per 16-col fragment (Q/K/V boundaries 2048/2560 are
// multiples of 16; a fragment never straddles a 64-col head).

__device__ __forceinline__ void stage10(const u16* Ap, const u16* Bp, u16* AsX,
                                        u16* BsX, int tid, int koff) {
#pragma unroll
  for (int i = 0; i < 4; i++)
    load16_to_lds(Ap + (size_t)(i * 32) * HID + koff, AsX + (i * 256 + tid) * 8);
#pragma unroll
  for (int i = 0; i < 6; i++)
    load16_to_lds(Bp + (size_t)(i * 32) * HID + koff, BsX + (i * 256 + tid) * 8);
}

__device__ __forceinline__ void frag46(const u16* Asb, const u16* Bsb,
                                       const int aoff[4][2], const int boff[6][2],
                                       f32x4 acc[4][6]) {
#pragma unroll
  for (int kk = 0; kk < 2; kk++) {
    bf16x8 a[4], b[6];
#pragma unroll
    for (int i = 0; i < 4; i++)
      a[i] = *(const bf16x8*)((const char*)Asb + aoff[i][kk]);
#pragma unroll
    for (int j = 0; j < 6; j++)
      b[j] = *(const bf16x8*)((const char*)Bsb + boff[j][kk]);
#pragma unroll
    for (int i = 0; i < 4; i++)
#pragma unroll
      for (int j = 0; j < 6; j++)
        acc[i][j] = __builtin_amdgcn_mfma_f32_16x16x32_bf16(a[i], b[j], acc[i][j], 0, 0, 0);
  }
}

#define Q_STEP(AsX, BsX, tnext)                                 \
  do {                                                          \
    asm volatile("s_waitcnt vmcnt(10)" ::: "memory");           \
    __builtin_amdgcn_sched_barrier(0);                          \
    __builtin_amdgcn_s_barrier();                               \
    frag46(AsX, BsX, aoff, boff, acc);                          \
    __builtin_amdgcn_sched_barrier(0);                          \
    __builtin_amdgcn_s_barrier();                               \
    stage10(Ap, Bp, AsX, BsX, tid, (tnext) * 64);               \
    __builtin_amdgcn_sched_barrier(0);                          \
  } while (0)

#define Q_TAIL(AsX, BsX, n)                                     \
  do {                                                          \
    asm volatile("s_waitcnt vmcnt(" #n ")" ::: "memory");       \
    __builtin_amdgcn_sched_barrier(0);                          \
    __builtin_amdgcn_s_barrier();                               \
    frag46(AsX, BsX, aoff, boff, acc);                          \
  } while (0)

__global__ __launch_bounds__(256) void k_gemm_qkv(const u16* __restrict__ A,
                                                  const u16* __restrict__ Bt,
                                                  const float* __restrict__ cosp,
                                                  const float* __restrict__ sinp,
                                                  u16* __restrict__ qbuf,
                                                  u16* __restrict__ kbuf,
                                                  u16* __restrict__ vtb) {
  __shared__ u16 smem[40960];  // 80KB: 2 x (A 16KB + B 24KB); Ts aliases 48KB
  u16* As0 = smem;             // [0, 8192)
  u16* As1 = smem + 8192;      // [8192, 16384)
  u16* Bs0 = smem + 16384;     // [16384, 28672)
  u16* Bs1 = smem + 28672;     // [28672, 40960)
  u16* Ts = smem;              // 48KB: 192 cols x 128 rows x 2B (V epilogue)
  int tid = threadIdx.x;
  // bijective XCD swizzle: XCD (= lin%8 heuristic) gets n-panels {2a, 2a+1}
  int lin = blockIdx.x;
  int wg = (lin & 7) * 32 + (lin >> 3);
  int m0 = (wg & 15) * 128, n0 = (wg >> 4) * 192;
  int l = tid & 63, w = tid >> 6;
  int lr = l & 15, lg = l >> 4;
  int wr = (w >> 1) * 64, wc = (w & 1) * 96;
  f32x4 acc[4][6] = {};
  int r8 = tid >> 3;
  int sx = (tid & 7) ^ (r8 & 7);
  const u16* Ap = A + (size_t)(m0 + r8) * HID + sx * 8;
  const u16* Bp = Bt + (size_t)(n0 + r8) * HID + sx * 8;
  int aoff[4][2], boff[6][2];
#pragma unroll
  for (int i = 0; i < 4; i++) {
    int ra = wr + i * 16 + lr;
#pragma unroll
    for (int kk = 0; kk < 2; kk++)
      aoff[i][kk] = ra * 128 + (((lg + kk * 4) ^ (ra & 7)) << 4);
  }
#pragma unroll
  for (int j = 0; j < 6; j++) {
    int rb = wc + j * 16 + lr;
#pragma unroll
    for (int kk = 0; kk < 2; kk++)
      boff[j][kk] = rb * 128 + (((lg + kk * 4) ^ (rb & 7)) << 4);
  }

  stage10(Ap, Bp, As0, Bs0, tid, 0);
  stage10(Ap, Bp, As1, Bs1, tid, 64);
#pragma unroll 1
  for (int t = 0; t < 30; t += 2) {
    Q_STEP(As0, Bs0, t + 2);
    Q_STEP(As1, Bs1, t + 3);
  }
  Q_TAIL(As0, Bs0, 10);
  Q_TAIL(As1, Bs1, 0);

  // ---- epilogue: per-fragment Q/K RoPE stores; V via Ts transpose ----
  int odd = lr & 1;
#pragma unroll
  for (int j = 0; j < 6; j++) {
    int colf = n0 + wc + j * 16;  // wave-uniform
    if (colf < 2560) {
      bool isQ = colf < 2048;
      float scale = isQ ? QSCALE : 1.0f;
      u16* base = isQ ? qbuf + (size_t)(colf >> 6) * SEQ * HD
                      : kbuf + (size_t)((colf - 2048) >> 6) * SEQ * HD;
      int ch = colf & 63;              // col-in-head base (multiple of 16)
      int ii = (ch >> 1) + (lr >> 1);  // RoPE pair index within head
#pragma unroll
      for (int i = 0; i < 4; i++)
#pragma unroll
        for (int r = 0; r < 4; r++) {
          float v = acc[i][j][r];
          float vp = __shfl_xor(v, 1, 64);
          int sr = m0 + wr + i * 16 + lg * 4 + r;
          float cs = cosp[sr * 32 + ii], sn = sinp[sr * 32 + ii];
          float x1 = odd ? vp : v, x2 = odd ? v : vp;
          float o = odd ? (x1 * sn + x2 * cs) : (x1 * cs - x2 * sn);
          base[(size_t)sr * HD + ch + lr] = f2bf(o * scale);
        }
    }
  }
  if (n0 + 192 > 2560) {  // block contains V columns
    __syncthreads();      // all waves done with pipeline LDS
#pragma unroll
    for (int j = 0; j < 6; j++) {
      int colf = n0 + wc + j * 16;
      if (colf >= 2560) {
#pragma unroll
        for (int i = 0; i < 4; i++)
#pragma unroll
          for (int r = 0; r < 4; r++) {
            int cB = wc + j * 16 + lr, rB = wr + i * 16 + lg * 4 + r;
            *(u16*)((char*)Ts + cB * 256 + ((rB * 2) ^ ((cB & 7) << 4))) =
                f2bf(acc[i][j][r]);
          }
      }
    }
    __syncthreads();
#pragma unroll
    for (int p = 0; p < 2; p++) {
      int c = p * 128 + (tid >> 1);
      if (c < 192 && n0 + c >= 2560) {
        int col = n0 + c;
        int half = tid & 1;
        int kvh = (col - 2560) >> 6, d = col & 63;
        u16* dst = vtb + (size_t)kvh * HD * SEQ + (size_t)d * SEQ + m0 + half * 64;
        const char* src = (const char*)Ts + c * 256;
        int cs7 = (c & 7) << 4;
#pragma unroll
        for (int q = 0; q < 8; q++)
          *(uint4*)(dst + q * 8) = *(const uint4*)(src + ((half * 128 + q * 16) ^ cs7));
      }
    }
  }
}

// ---------- Flash attention pass 1: KV-split x2, partial O + (m,l) ----------
__global__ __launch_bounds__(256) void k_flash2(const u16* __restrict__ qb,
                                                const u16* __restrict__ kb,
                                                const u16* __restrict__ vt,
                                                unsigned* __restrict__ Opart,
                                                float2* __restrict__ ml) {
  __shared__ u16 Ks[2][64 * 64];
  __shared__ u16 Vs[2][64 * 64];
  int bid = blockIdx.x;
  int c = bid & 1;                  // chunk fastest
  int b5 = bid >> 1;                // 0..511
  int h = b5 & 31;                  // heads next
  int qi = b5 >> 5;
  int qblk = (SEQ / 128) - 1 - qi;  // LPT: heaviest first
  int kvh = h & 7;
  int tid = threadIdx.x, w = tid >> 6, l = tid & 63;
  int lq = l & 31, hi = l >> 5;
  const u16* qh = qb + (size_t)h * SEQ * HD;
  const u16* kh = kb + (size_t)kvh * SEQ * HD;
  const u16* vh = vt + (size_t)kvh * HD * SEQ;
  int wq0 = qblk * 128 + w * 32;
  int qg = wq0 + lq;

  bf16x8 qf[4];
#pragma unroll
  for (int ds = 0; ds < 4; ds++)
    qf[ds] = *(const bf16x8*)(qh + (size_t)qg * HD + ds * 16 + hi * 8);

  f32x16 acc[2] = {};   // O^T: lane: q=l&31, d = dt*32 + (r&3)+8*(r>>2)+4*hi
  float m_r = -__builtin_inff(), l_r = 0.f;

  int srow = tid >> 2, c4 = tid & 3, swz = (srow & 7) << 4;
  int sd0 = srow * 128 + ((c4 * 32) ^ swz);
  int sd1 = srow * 128 + ((c4 * 32 + 16) ^ swz);
  const int kt0 = c * (qblk + 1), kt1 = kt0 + qblk + 1;

  // prologue: stage tile kt0
  {
    const u16* ksrc = kh + (size_t)(kt0 * 64 + srow) * HD + c4 * 16;
    const u16* vsrc = vh + (size_t)srow * SEQ + kt0 * 64 + c4 * 16;
    uint4 a0 = *(const uint4*)(ksrc), a1 = *(const uint4*)(ksrc + 8);
    uint4 b0 = *(const uint4*)(vsrc), b1 = *(const uint4*)(vsrc + 8);
    *(uint4*)((char*)Ks[0] + sd0) = a0; *(uint4*)((char*)Ks[0] + sd1) = a1;
    *(uint4*)((char*)Vs[0] + sd0) = b0; *(uint4*)((char*)Vs[0] + sd1) = b1;
  }
  __syncthreads();

  uint4 kr0, kr1, vr0, vr1;
  int lswz = (lq & 7) << 4;
  for (int kt = kt0; kt < kt1; kt++) {
    int b = (kt - kt0) & 1;
    if (kt + 1 < kt1) {
      const u16* ksrc = kh + (size_t)((kt + 1) * 64 + srow) * HD + c4 * 16;
      const u16* vsrc = vh + (size_t)srow * SEQ + (kt + 1) * 64 + c4 * 16;
      kr0 = *(const uint4*)(ksrc); kr1 = *(const uint4*)(ksrc + 8);
      vr0 = *(const uint4*)(vsrc); vr1 = *(const uint4*)(vsrc + 8);
    }

    if (kt * 64 <= wq0 + 31) {  // skip fully-masked tiles
      f32x16 sT[2] = {};
      const char* kbase = (const char*)Ks[b];
      __builtin_amdgcn_s_setprio(1);
#pragma unroll
      for (int t = 0; t < 2; t++) {
#pragma unroll
        for (int ds = 0; ds < 4; ds++) {
          bf16x8 kf = *(const bf16x8*)(kbase + (t * 32 + lq) * 128 +
                                       ((ds * 32 + hi * 16) ^ lswz));
          sT[t] = __builtin_amdgcn_mfma_f32_32x32x16_bf16(kf, qf[ds], sT[t], 0, 0, 0);
        }
      }
      __builtin_amdgcn_s_setprio(0);

      if (kt * 64 + 63 > wq0) {
#pragma unroll
        for (int t = 0; t < 2; t++)
#pragma unroll
          for (int r = 0; r < 16; r++) {
            int kg = kt * 64 + t * 32 + (r & 3) + 8 * (r >> 2) + 4 * hi;
            if (kg > qg) sT[t][r] = -__builtin_inff();
          }
      }

      float pmax = sT[0][0];
#pragma unroll
      for (int r = 1; r < 16; r++) pmax = fmaxf(pmax, sT[0][r]);
#pragma unroll
      for (int r = 0; r < 16; r++) pmax = fmaxf(pmax, sT[1][r]);
      pmax = fmaxf(pmax, __shfl_xor(pmax, 32, 64));

      if (!__all(pmax <= m_r + 8.f)) {
        float mn = fmaxf(m_r, pmax);
        float scl = __builtin_amdgcn_exp2f(m_r - mn);
        l_r *= scl;
        acc[0] *= scl;
        acc[1] *= scl;
        m_r = mn;
      }

      float ss = 0.f;
#pragma unroll
      for (int t = 0; t < 2; t++)
#pragma unroll
        for (int r = 0; r < 16; r++) {
          float p = __builtin_amdgcn_exp2f(sT[t][r] - m_r);
          sT[t][r] = p;
          ss += p;
        }
      ss += __shfl_xor(ss, 32, 64);
      l_r += ss;

      const char* vbase = (const char*)Vs[b];
#pragma unroll
      for (int t = 0; t < 2; t++) {
        unsigned cp[4][2];
#pragma unroll
        for (int m = 0; m < 4; m++) {
          cp[m][0] = pk2(sT[t][4 * m + 0], sT[t][4 * m + 1]);
          cp[m][1] = pk2(sT[t][4 * m + 2], sT[t][4 * m + 3]);
        }
#pragma unroll
        for (int kl = 0; kl < 2; kl++) {
          unsigned s0 = hi ? cp[2 * kl][0] : cp[2 * kl + 1][0];
          unsigned s1 = hi ? cp[2 * kl][1] : cp[2 * kl + 1][1];
          unsigned r0 = (unsigned)__shfl_xor((int)s0, 32, 64);
          unsigned r1 = (unsigned)__shfl_xor((int)s1, 32, 64);
          union { unsigned u[4]; bf16x8 v; } pa;
          pa.u[0] = hi ? r0 : cp[2 * kl][0];
          pa.u[1] = hi ? r1 : cp[2 * kl][1];
          pa.u[2] = hi ? cp[2 * kl + 1][0] : r0;
          pa.u[3] = hi ? cp[2 * kl + 1][1] : r1;
          int ks = t * 2 + kl;
          __builtin_amdgcn_s_setprio(1);
#pragma unroll
          for (int dt = 0; dt < 2; dt++) {
            bf16x8 vb = *(const bf16x8*)(vbase + (dt * 32 + lq) * 128 +
                                         ((ks * 32 + hi * 16) ^ lswz));
            acc[dt] = __builtin_amdgcn_mfma_f32_32x32x16_bf16(vb, pa.v, acc[dt], 0, 0, 0);
          }
          __builtin_amdgcn_s_setprio(0);
        }
      }
    }

    if (kt + 1 < kt1) {
      *(uint4*)((char*)Ks[b ^ 1] + sd0) = kr0;
      *(uint4*)((char*)Ks[b ^ 1] + sd1) = kr1;
      *(uint4*)((char*)Vs[b ^ 1] + sd0) = vr0;
      *(uint4*)((char*)Vs[b ^ 1] + sd1) = vr1;
    }
    __syncthreads();
  }

  // epilogue: dump raw-lane-layout partial O (bf16 pairs) + (m,l), coalesced
  unsigned* op = Opart + (size_t)c * OCH + ((size_t)(b5 * 4 + w) * 16) * 64;
#pragma unroll
  for (int dt = 0; dt < 2; dt++)
#pragma unroll
    for (int j = 0; j < 8; j++)
      op[(dt * 8 + j) * 64 + l] = pk2(acc[dt][2 * j], acc[dt][2 * j + 1]);
  if (!hi)
    ml[c * (HEADS * SEQ) + h * SEQ + wq0 + lq] = make_float2(m_r, l_r);
}

// ---------- Flash pass 2: merge chunk partials, transpose, write av ----------
__global__ __launch_bounds__(256) void k_merge(const unsigned* __restrict__ Opart,
                                               const float2* __restrict__ ml,
                                               u16* __restrict__ av) {
  __shared__ u16 Ts[8192];  // 16KB: 4 waves x 4KB transpose staging
  int bid = blockIdx.x;
  int h = bid & 31, qblk = bid >> 5;
  int b5 = ((SEQ / 128 - 1 - qblk) << 5) | h;  // pass-1 flat block index
  int tid = threadIdx.x, w = tid >> 6, l = tid & 63;
  int lq = l & 31, hi = l >> 5;
  int wq0 = qblk * 128 + w * 32;

  float2 ml0 = ml[h * SEQ + wq0 + lq];
  float2 ml1 = ml[HEADS * SEQ + h * SEQ + wq0 + lq];
  float m = fmaxf(ml0.x, ml1.x);
  float f0 = __builtin_amdgcn_exp2f(ml0.x - m);
  float f1 = __builtin_amdgcn_exp2f(ml1.x - m);
  float inv = 1.0f / (ml0.y * f0 + ml1.y * f1);

  const unsigned* op0 = Opart + ((size_t)(b5 * 4 + w) * 16) * 64;
  const unsigned* op1 = op0 + OCH;
  f32x16 acc[2];
#pragma unroll
  for (int dt = 0; dt < 2; dt++)
#pragma unroll
    for (int j = 0; j < 8; j++) {
      unsigned a0 = op0[(dt * 8 + j) * 64 + l];
      unsigned a1 = op1[(dt * 8 + j) * 64 + l];
      acc[dt][2 * j] = bflo(a0) * f0 + bflo(a1) * f1;
      acc[dt][2 * j + 1] = bfhi(a0) * f0 + bfhi(a1) * f1;
    }

  // LDS transpose epilogue (identical to R6 flash)
  int lswz = (lq & 7) << 4;
  char* wbase = (char*)Ts + w * 4096;
#pragma unroll
  for (int dt = 0; dt < 2; dt++)
#pragma unroll
    for (int m4 = 0; m4 < 4; m4++) {
      int r0 = 4 * m4;
      uint2 pr;
      pr.x = pk2(acc[dt][r0 + 0] * inv, acc[dt][r0 + 1] * inv);
      pr.y = pk2(acc[dt][r0 + 2] * inv, acc[dt][r0 + 3] * inv);
      int byte = lq * 128 + ((dt * 64 + m4 * 16 + hi * 8) ^ lswz);
      *(uint2*)(wbase + byte) = pr;
    }
  __syncthreads();
  int q2 = l >> 1, cH = l & 1;
  int qswz = (q2 & 7) << 4;
#pragma unroll
  for (int i = 0; i < 4; i++) {
    uint4 d = *(const uint4*)(wbase + q2 * 128 + ((cH * 64 + i * 16) ^ qswz));
    *(uint4*)(av + (size_t)(wq0 + q2) * HID + h * HD + cH * 32 + i * 8) = d;
  }
}

extern "C" void kernel_launch(void* const* d_in, const int* in_sizes, int n_in,
                              void* d_out, int out_size, void* d_ws, size_t ws_size,
                              hipStream_t stream) {
  (void)in_sizes; (void)n_in; (void)out_size; (void)ws_size;
  const float* x = (const float*)d_in[0];
  const float* cosp = (const float*)d_in[1];
  const float* sinp = (const float*)d_in[2];
  const float* Wq = (const float*)d_in[3];
  const float* Wk = (const float*)d_in[4];
  const float* Wv = (const float*)d_in[5];
  const float* Wo = (const float*)d_in[6];
  float* out = (float*)d_out;
  char* ws = (char*)d_ws;

  // workspace layout (64 MiB exactly):
  u16* xb = (u16*)(ws);                          // [0,8M)   x bf16; dead after qkv
  float2* mlb = (float2*)(ws);                   // [0,1M)   aliases dead xb (flash2+)
  u16* Wqkv = (u16*)(ws + ((size_t)8 << 20));    // [8,20M)  Wq^T|Wk^T|Wv^T
  u16* WoT = (u16*)(ws + ((size_t)20 << 20));    // [20,28M) Wo^T
  u16* qbuf = (u16*)(ws + ((size_t)28 << 20));   // [28,36M) q rope bf16 [32][S][64]
  u16* kbuf = (u16*)(ws + ((size_t)36 << 20));   // [36,38M) k rope bf16 [8][S][64]
  u16* vtb = (u16*)(ws + ((size_t)38 << 20));    // [38,40M) v^T bf16 [8][64][S]
  u16* av = (u16*)(ws + ((size_t)40 << 20));     // [40,48M) av bf16 [S][2048]
  unsigned* Opart = (unsigned*)(ws + ((size_t)48 << 20));  // [48,64M) 2 chunks x 8M

  k_f2b<<<(SEQ * HID / 4 + 255) / 256, 256, 0, stream>>>(x, xb, SEQ * HID / 4);
  k_tconv<<<dim3(HID / 32, HID / 32), 256, 0, stream>>>(Wq, HID, Wqkv, HID);
  k_tconv<<<dim3(512 / 32, HID / 32), 256, 0, stream>>>(Wk, 512, Wqkv + (size_t)2048 * HID, HID);
  k_tconv<<<dim3(512 / 32, HID / 32), 256, 0, stream>>>(Wv, 512, Wqkv + (size_t)2560 * HID, HID);
  k_tconv<<<dim3(HID / 32, HID / 32), 256, 0, stream>>>(Wo, HID, WoT, HID);
  k_gemm_qkv<<<256, 256, 0, stream>>>(xb, Wqkv, cosp, sinp, qbuf, kbuf, vtb);
  k_flash2<<<(SEQ / 128) * HEADS * 2, 256, 0, stream>>>(qbuf, kbuf, vtb, Opart, mlb);
  k_merge<<<(SEQ / 128) * HEADS, 256, 0, stream>>>(Opart, mlb, av);
  k_gemm<<<dim3(SEQ / 128, HID / 128), 256, 0, stream>>>(av, WoT, out, SEQ, HID, HID);
}

// Round 7
// 129.184 us; speedup vs baseline: 1.2681x; 1.0017x over previous
//
#include <hip/hip_runtime.h>

typedef unsigned short u16;
typedef __attribute__((ext_vector_type(4))) float f32x4;
typedef __attribute__((ext_vector_type(16))) float f32x16;
typedef __attribute__((ext_vector_type(8))) __bf16 bf16x8;
typedef __attribute__((ext_vector_type(2))) __bf16 bf16x2;

#define HEADS 32
#define KV_HEADS 8
#define HD 64
#define SEQ 2048
#define HID 2048
#define NQK 3072  // 2048 (Q) + 512 (K) + 512 (V)
#define QSCALE (0.125f * 1.4426950408889634f)  // exp2-domain softmax
#define OCH 2097152u  // u32s per partial-O chunk (512 blk * 4 waves * 16 * 64)

#define AS1 __attribute__((address_space(1)))
#define AS3 __attribute__((address_space(3)))

__device__ __forceinline__ u16 f2bf(float f) {
  unsigned u = __float_as_uint(f);
  u += 0x7FFFu + ((u >> 16) & 1u);
  return (u16)(u >> 16);
}

__device__ __forceinline__ unsigned pk2(float a, float b) {
  union { bf16x2 h; unsigned u; } c;
  c.h[0] = (__bf16)a; c.h[1] = (__bf16)b;
  return c.u;
}

__device__ __forceinline__ float bflo(unsigned u) {
  return __uint_as_float(u << 16);
}
__device__ __forceinline__ float bfhi(unsigned u) {
  return __uint_as_float(u & 0xFFFF0000u);
}

__device__ __forceinline__ void load16_to_lds(const void* g, void* l) {
  __builtin_amdgcn_global_load_lds((AS1 void*)(void*)g, (AS3 void*)l, 16, 0, 0);
}

// ---------- fp32 -> bf16 elementwise (4 elems/thread) ----------
__global__ __launch_bounds__(256) void k_f2b(const float* __restrict__ in,
                                             u16* __restrict__ out, int n4) {
  int i = blockIdx.x * 256 + threadIdx.x;
  if (i >= n4) return;
  float4 v = ((const float4*)in)[i];
  ushort4 o;
  o.x = f2bf(v.x); o.y = f2bf(v.y); o.z = f2bf(v.z); o.w = f2bf(v.w);
  ((ushort4*)out)[i] = o;
}

// ---------- transpose + convert: out[c*ldo + r] = bf16(in[r*ldi + c]) ----------
__global__ __launch_bounds__(256) void k_tconv(const float* __restrict__ in, int ldi,
                                               u16* __restrict__ out, int ldo) {
  __shared__ float tile[32][33];
  int c0 = blockIdx.x * 32, r0 = blockIdx.y * 32;
  int col = threadIdx.x & 31, rw = threadIdx.x >> 5;
#pragma unroll
  for (int i = 0; i < 4; i++)
    tile[rw + i * 8][col] = in[(size_t)(r0 + rw + i * 8) * ldi + c0 + col];
  __syncthreads();
#pragma unroll
  for (int i = 0; i < 4; i++)
    out[(size_t)(c0 + rw + i * 8) * ldo + r0 + col] = f2bf(tile[col][rw + i * 8]);
}

// ======================= out-proj GEMM (R3 template + XCD swizzle) ==========
// 128x128 block tile, BK=64, 4 waves each 64x64 quadrant, depth-2 counted
// vmcnt pipeline, 8-slot source-swizzle (measured conflict-free in R3).
// Grid 256 (1D) = 1 block/CU; XCD swizzle: each XCD owns 2 B-panels.

__device__ __forceinline__ void stage8(const u16* Ap, const u16* Bp, u16* AsX,
                                       u16* BsX, int tid, int K, int koff) {
#pragma unroll
  for (int i = 0; i < 4; i++) {
    load16_to_lds(Ap + (size_t)(i * 32) * K + koff, AsX + (i * 256 + tid) * 8);
    load16_to_lds(Bp + (size_t)(i * 32) * K + koff, BsX + (i * 256 + tid) * 8);
  }
}

__device__ __forceinline__ void frag16(const u16* Asb, const u16* Bsb,
                                       const int aoff[4][2], const int boff[4][2],
                                       f32x4 acc[4][4]) {
#pragma unroll
  for (int kk = 0; kk < 2; kk++) {
    bf16x8 a[4], b[4];
#pragma unroll
    for (int i = 0; i < 4; i++)
      a[i] = *(const bf16x8*)((const char*)Asb + aoff[i][kk]);
#pragma unroll
    for (int j = 0; j < 4; j++)
      b[j] = *(const bf16x8*)((const char*)Bsb + boff[j][kk]);
#pragma unroll
    for (int i = 0; i < 4; i++)
#pragma unroll
      for (int j = 0; j < 4; j++)
        acc[i][j] = __builtin_amdgcn_mfma_f32_16x16x32_bf16(a[i], b[j], acc[i][j], 0, 0, 0);
  }
}

#define TILE_STEP(AsX, BsX, tnext)                              \
  do {                                                          \
    asm volatile("s_waitcnt vmcnt(8)" ::: "memory");            \
    __builtin_amdgcn_sched_barrier(0);                          \
    __builtin_amdgcn_s_barrier();                               \
    frag16(AsX, BsX, aoff, boff, acc);                          \
    __builtin_amdgcn_sched_barrier(0);                          \
    __builtin_amdgcn_s_barrier();                               \
    stage8(Ap, Bp, AsX, BsX, tid, K, (tnext) * 64);             \
    __builtin_amdgcn_sched_barrier(0);                          \
  } while (0)

#define TILE_TAIL(AsX, BsX, n)                                  \
  do {                                                          \
    asm volatile("s_waitcnt vmcnt(" #n ")" ::: "memory");       \
    __builtin_amdgcn_sched_barrier(0);                          \
    __builtin_amdgcn_s_barrier();                               \
    frag16(AsX, BsX, aoff, boff, acc);                          \
  } while (0)

__global__ __launch_bounds__(256) void k_gemm(const u16* __restrict__ A,
                                              const u16* __restrict__ Bt,
                                              float* __restrict__ C,
                                              int M, int N, int K) {
  __shared__ u16 smem[32768];  // 64KB: 2 x (A 16KB + B 16KB)
  u16* As0 = smem;          u16* As1 = smem + 8192;
  u16* Bs0 = smem + 16384;  u16* Bs1 = smem + 24576;
  int tid = threadIdx.x;
  // XCD swizzle: grid 256 (16x16); XCD (= bid%8 heuristic) owns 2 B-panels
  int bid = blockIdx.x;
  int wg = (bid & 7) * 32 + (bid >> 3);
  int m0 = (wg & 15) * 128, n0 = (wg >> 4) * 128;
  int l = tid & 63, w = tid >> 6;
  int lr = l & 15, lg = l >> 4;
  int wr = (w >> 1) * 64, wc = (w & 1) * 64;
  f32x4 acc[4][4] = {};
  int r8 = tid >> 3;
  int sx = (tid & 7) ^ (r8 & 7);
  const u16* Ap = A + (size_t)(m0 + r8) * K + sx * 8;
  const u16* Bp = Bt + (size_t)(n0 + r8) * K + sx * 8;
  int aoff[4][2], boff[4][2];
#pragma unroll
  for (int i = 0; i < 4; i++) {
    int ra = wr + i * 16 + lr;
    int rb = wc + i * 16 + lr;
#pragma unroll
    for (int kk = 0; kk < 2; kk++) {
      aoff[i][kk] = ra * 128 + (((lg + kk * 4) ^ (ra & 7)) << 4);
      boff[i][kk] = rb * 128 + (((lg + kk * 4) ^ (rb & 7)) << 4);
    }
  }
  stage8(Ap, Bp, As0, Bs0, tid, K, 0);
  stage8(Ap, Bp, As1, Bs1, tid, K, 64);
#pragma unroll 1
  for (int t = 0; t < 30; t += 2) {
    TILE_STEP(As0, Bs0, t + 2);
    TILE_STEP(As1, Bs1, t + 3);
  }
  TILE_TAIL(As0, Bs0, 8);
  TILE_TAIL(As1, Bs1, 0);

#pragma unroll
  for (int i = 0; i < 4; i++)
#pragma unroll
    for (int j = 0; j < 4; j++)
#pragma unroll
      for (int r = 0; r < 4; r++)
        C[(size_t)(m0 + wr + i * 16 + lg * 4 + r) * N + n0 + wc + j * 16 + lr] =
            acc[i][j][r];
}

// ======================= QKV GEMM (R7: 64-phase BK=32 depth-3) ==============
// 128x128 tile, 4 waves (64x64 each).  64 phases of K=32; 3 rotating 16KB
// buffer sets (48KB LDS -> 2-3 blocks/CU co-resident for TLP).  ONE barrier
// per phase; stage(p+2) issued inside phase p right after the frag reads
// (target = buffer read at p-1, whose reads retired before barrier p).
// Steady state 8 loads in flight, wait vmcnt(4) — never drained.
// LDS layout: two K=32 rows packed per 128B line.  line = r>>1; the 16B slot
// holding (r, kseg lg) is ((r&1)*4 + lg) ^ (line&7).  Verified conflict-free:
// any 8 consecutive lanes of a frag read cover slots {l..l+3} U ({l..l+3}^4)
// = all 8 slots.  gload_lds dest stays LINEAR; the same involution is applied
// to the per-thread GLOBAL source (row/kseg derived from the physical slot).

#define QSTAGE(Sw, KN)                                                  \
  do {                                                                  \
    load16_to_lds(Ag0 + (size_t)(KN) * 32, (Sw) + tid * 8);             \
    load16_to_lds(Ag1 + (size_t)(KN) * 32, (Sw) + (256 + tid) * 8);     \
    load16_to_lds(Bg0 + (size_t)(KN) * 32, (Sw) + 4096 + tid * 8);      \
    load16_to_lds(Bg1 + (size_t)(KN) * 32, (Sw) + 4096 + (256 + tid) * 8); \
  } while (0)

#define QPH(Sc, DOSTAGE, Sw, KN, VM)                                    \
  do {                                                                  \
    asm volatile("s_waitcnt vmcnt(" #VM ")" ::: "memory");              \
    __builtin_amdgcn_sched_barrier(0);                                  \
    __builtin_amdgcn_s_barrier();                                       \
    bf16x8 a_[4], b_[4];                                                \
    _Pragma("unroll") for (int i_ = 0; i_ < 4; i_++) {                  \
      a_[i_] = *(const bf16x8*)((const char*)(Sc) + aoff[i_]);          \
      b_[i_] = *(const bf16x8*)((const char*)(Sc) + 8192 + boff[i_]);   \
    }                                                                   \
    if (DOSTAGE) QSTAGE(Sw, KN);                                        \
    __builtin_amdgcn_sched_barrier(0);                                  \
    __builtin_amdgcn_s_setprio(1);                                      \
    _Pragma("unroll") for (int i_ = 0; i_ < 4; i_++)                    \
      _Pragma("unroll") for (int j_ = 0; j_ < 4; j_++)                  \
        acc[i_][j_] = __builtin_amdgcn_mfma_f32_16x16x32_bf16(          \
            a_[i_], b_[j_], acc[i_][j_], 0, 0, 0);                      \
    __builtin_amdgcn_s_setprio(0);                                      \
  } while (0)

__global__ __launch_bounds__(256) void k_gemm_qkv(const u16* __restrict__ A,
                                                  const u16* __restrict__ Bt,
                                                  const float* __restrict__ cosp,
                                                  const float* __restrict__ sinp,
                                                  u16* __restrict__ qbuf,
                                                  u16* __restrict__ kbuf,
                                                  u16* __restrict__ vtb) {
  __shared__ u16 smem[24576];  // 48KB: 3 sets x (A 8KB + B 8KB)
  u16* S0 = smem;
  u16* S1 = smem + 8192;
  u16* S2 = smem + 16384;
  u16* Ts = smem;              // 32KB V-transpose staging (post-loop only)
  int tid = threadIdx.x;
  // XCD swizzle: grid 384 (16x24); XCD (= bid%8 heuristic) owns 3 B-panels
  int bid = blockIdx.x;
  int wg = (bid & 7) * 48 + (bid >> 3);
  int m0 = (wg & 15) * 128, n0 = (wg >> 4) * 128;
  int l = tid & 63, w = tid >> 6;
  int lr = l & 15, lg = l >> 4;
  int wr = (w >> 1) * 64, wc = (w & 1) * 64;
  f32x4 acc[4][4] = {};

  // staging source addresses: thread covers physical slots tid and tid+256
  int l0_ = tid >> 3, p0_ = tid & 7, x0_ = p0_ ^ (l0_ & 7);
  int r0_ = 2 * l0_ + (x0_ >> 2), k0_ = x0_ & 3;
  int si1 = tid + 256;
  int l1_ = si1 >> 3, p1_ = si1 & 7, x1_ = p1_ ^ (l1_ & 7);
  int r1_ = 2 * l1_ + (x1_ >> 2), k1_ = x1_ & 3;
  const u16* Ag0 = A + (size_t)(m0 + r0_) * HID + k0_ * 8;
  const u16* Ag1 = A + (size_t)(m0 + r1_) * HID + k1_ * 8;
  const u16* Bg0 = Bt + (size_t)(n0 + r0_) * HID + k0_ * 8;
  const u16* Bg1 = Bt + (size_t)(n0 + r1_) * HID + k1_ * 8;

  // fragment read byte-offsets (within A region; B adds +8192)
  int aoff[4], boff[4];
#pragma unroll
  for (int i = 0; i < 4; i++) {
    int ra = wr + i * 16 + lr, rb = wc + i * 16 + lr;
    aoff[i] = (ra >> 1) * 128 + (((((ra & 1) << 2) | lg) ^ ((ra >> 1) & 7)) << 4);
    boff[i] = (rb >> 1) * 128 + (((((rb & 1) << 2) | lg) ^ ((rb >> 1) & 7)) << 4);
  }

  QSTAGE(S0, 0);
  QSTAGE(S1, 1);
#pragma unroll 1
  for (int t = 0; t < 60; t += 3) {
    QPH(S0, true, S2, t + 2, 4);
    QPH(S1, true, S0, t + 3, 4);
    QPH(S2, true, S1, t + 4, 4);
  }
  QPH(S0, true, S2, 62, 4);   // phase 60
  QPH(S1, true, S0, 63, 4);   // phase 61
  QPH(S2, false, S0, 0, 4);   // phase 62
  QPH(S0, false, S1, 0, 0);   // phase 63

  if (n0 < 2560) {
    // ---- Q or K: fused RoPE, direct bf16 stores (head-major) ----
    int colbase = n0 + wc;
    bool isQ = colbase < 2048;
    float scale = isQ ? QSCALE : 1.0f;
    u16* base = isQ ? qbuf + (size_t)(colbase >> 6) * SEQ * HD
                    : kbuf + (size_t)((colbase - 2048) >> 6) * SEQ * HD;
    int odd = lr & 1;
#pragma unroll
    for (int i = 0; i < 4; i++)
#pragma unroll
      for (int j = 0; j < 4; j++) {
        int ii = j * 8 + (lr >> 1);
#pragma unroll
        for (int r = 0; r < 4; r++) {
          float v = acc[i][j][r];
          float vp = __shfl_xor(v, 1, 64);
          int sr = m0 + wr + i * 16 + lg * 4 + r;
          float cs = cosp[sr * 32 + ii], sn = sinp[sr * 32 + ii];
          float x1 = odd ? vp : v, x2 = odd ? v : vp;
          float o = odd ? (x1 * sn + x2 * cs) : (x1 * cs - x2 * sn);
          base[(size_t)sr * HD + j * 16 + lr] = f2bf(o * scale);
        }
      }
  } else {
    // ---- V: LDS transpose -> coalesced vtb writes (Ts aliases pipe bufs) ----
    __syncthreads();  // all waves done reading pipeline buffers
#pragma unroll
    for (int i = 0; i < 4; i++)
#pragma unroll
      for (int j = 0; j < 4; j++)
#pragma unroll
        for (int r = 0; r < 4; r++) {
          int cB = wc + j * 16 + lr, rB = wr + i * 16 + lg * 4 + r;
          *(u16*)((char*)Ts + cB * 256 + ((rB * 2) ^ ((cB & 7) << 4))) =
              f2bf(acc[i][j][r]);
        }
    __syncthreads();
    int c = tid >> 1, half = tid & 1;
    int col = n0 + c;
    int kvh = (col - 2560) >> 6, d = col & 63;
    u16* dst = vtb + (size_t)kvh * HD * SEQ + (size_t)d * SEQ + m0 + half * 64;
    const char* src = (const char*)Ts + c * 256;
    int cs7 = (c & 7) << 4;
#pragma unroll
    for (int q = 0; q < 8; q++)
      *(uint4*)(dst + q * 8) = *(const uint4*)(src + ((half * 128 + q * 16) ^ cs7));
  }
}

// ---------- Flash attention pass 1: KV-split x2, partial O + (m,l) ----------
__global__ __launch_bounds__(256) void k_flash2(const u16* __restrict__ qb,
                                                const u16* __restrict__ kb,
                                                const u16* __restrict__ vt,
                                                unsigned* __restrict__ Opart,
                                                float2* __restrict__ ml) {
  __shared__ u16 Ks[2][64 * 64];
  __shared__ u16 Vs[2][64 * 64];
  int bid = blockIdx.x;
  int c = bid & 1;                  // chunk fastest
  int b5 = bid >> 1;                // 0..511
  int h = b5 & 31;                  // heads next
  int qi = b5 >> 5;
  int qblk = (SEQ / 128) - 1 - qi;  // LPT: heaviest first
  int kvh = h & 7;
  int tid = threadIdx.x, w = tid >> 6, l = tid & 63;
  int lq = l & 31, hi = l >> 5;
  const u16* qh = qb + (size_t)h * SEQ * HD;
  const u16* kh = kb + (size_t)kvh * SEQ * HD;
  const u16* vh = vt + (size_t)kvh * HD * SEQ;
  int wq0 = qblk * 128 + w * 32;
  int qg = wq0 + lq;

  bf16x8 qf[4];
#pragma unroll
  for (int ds = 0; ds < 4; ds++)
    qf[ds] = *(const bf16x8*)(qh + (size_t)qg * HD + ds * 16 + hi * 8);

  f32x16 acc[2] = {};   // O^T: lane: q=l&31, d = dt*32 + (r&3)+8*(r>>2)+4*hi
  float m_r = -__builtin_inff(), l_r = 0.f;

  int srow = tid >> 2, c4 = tid & 3, swz = (srow & 7) << 4;
  int sd0 = srow * 128 + ((c4 * 32) ^ swz);
  int sd1 = srow * 128 + ((c4 * 32 + 16) ^ swz);
  const int kt0 = c * (qblk + 1), kt1 = kt0 + qblk + 1;

  // prologue: stage tile kt0
  {
    const u16* ksrc = kh + (size_t)(kt0 * 64 + srow) * HD + c4 * 16;
    const u16* vsrc = vh + (size_t)srow * SEQ + kt0 * 64 + c4 * 16;
    uint4 a0 = *(const uint4*)(ksrc), a1 = *(const uint4*)(ksrc + 8);
    uint4 b0 = *(const uint4*)(vsrc), b1 = *(const uint4*)(vsrc + 8);
    *(uint4*)((char*)Ks[0] + sd0) = a0; *(uint4*)((char*)Ks[0] + sd1) = a1;
    *(uint4*)((char*)Vs[0] + sd0) = b0; *(uint4*)((char*)Vs[0] + sd1) = b1;
  }
  __syncthreads();

  uint4 kr0, kr1, vr0, vr1;
  int lswz = (lq & 7) << 4;
  for (int kt = kt0; kt < kt1; kt++) {
    int b = (kt - kt0) & 1;
    if (kt + 1 < kt1) {
      const u16* ksrc = kh + (size_t)((kt + 1) * 64 + srow) * HD + c4 * 16;
      const u16* vsrc = vh + (size_t)srow * SEQ + (kt + 1) * 64 + c4 * 16;
      kr0 = *(const uint4*)(ksrc); kr1 = *(const uint4*)(ksrc + 8);
      vr0 = *(const uint4*)(vsrc); vr1 = *(const uint4*)(vsrc + 8);
    }

    if (kt * 64 <= wq0 + 31) {  // skip fully-masked tiles
      f32x16 sT[2] = {};
      const char* kbase = (const char*)Ks[b];
      __builtin_amdgcn_s_setprio(1);
#pragma unroll
      for (int t = 0; t < 2; t++) {
#pragma unroll
        for (int ds = 0; ds < 4; ds++) {
          bf16x8 kf = *(const bf16x8*)(kbase + (t * 32 + lq) * 128 +
                                       ((ds * 32 + hi * 16) ^ lswz));
          sT[t] = __builtin_amdgcn_mfma_f32_32x32x16_bf16(kf, qf[ds], sT[t], 0, 0, 0);
        }
      }
      __builtin_amdgcn_s_setprio(0);

      if (kt * 64 + 63 > wq0) {
#pragma unroll
        for (int t = 0; t < 2; t++)
#pragma unroll
          for (int r = 0; r < 16; r++) {
            int kg = kt * 64 + t * 32 + (r & 3) + 8 * (r >> 2) + 4 * hi;
            if (kg > qg) sT[t][r] = -__builtin_inff();
          }
      }

      float pmax = sT[0][0];
#pragma unroll
      for (int r = 1; r < 16; r++) pmax = fmaxf(pmax, sT[0][r]);
#pragma unroll
      for (int r = 0; r < 16; r++) pmax = fmaxf(pmax, sT[1][r]);
      pmax = fmaxf(pmax, __shfl_xor(pmax, 32, 64));

      if (!__all(pmax <= m_r + 8.f)) {
        float mn = fmaxf(m_r, pmax);
        float scl = __builtin_amdgcn_exp2f(m_r - mn);
        l_r *= scl;
        acc[0] *= scl;
        acc[1] *= scl;
        m_r = mn;
      }

      float ss = 0.f;
#pragma unroll
      for (int t = 0; t < 2; t++)
#pragma unroll
        for (int r = 0; r < 16; r++) {
          float p = __builtin_amdgcn_exp2f(sT[t][r] - m_r);
          sT[t][r] = p;
          ss += p;
        }
      ss += __shfl_xor(ss, 32, 64);
      l_r += ss;

      const char* vbase = (const char*)Vs[b];
#pragma unroll
      for (int t = 0; t < 2; t++) {
        unsigned cp[4][2];
#pragma unroll
        for (int m = 0; m < 4; m++) {
          cp[m][0] = pk2(sT[t][4 * m + 0], sT[t][4 * m + 1]);
          cp[m][1] = pk2(sT[t][4 * m + 2], sT[t][4 * m + 3]);
        }
#pragma unroll
        for (int kl = 0; kl < 2; kl++) {
          unsigned s0 = hi ? cp[2 * kl][0] : cp[2 * kl + 1][0];
          unsigned s1 = hi ? cp[2 * kl][1] : cp[2 * kl + 1][1];
          unsigned r0 = (unsigned)__shfl_xor((int)s0, 32, 64);
          unsigned r1 = (unsigned)__shfl_xor((int)s1, 32, 64);
          union { unsigned u[4]; bf16x8 v; } pa;
          pa.u[0] = hi ? r0 : cp[2 * kl][0];
          pa.u[1] = hi ? r1 : cp[2 * kl][1];
          pa.u[2] = hi ? cp[2 * kl + 1][0] : r0;
          pa.u[3] = hi ? cp[2 * kl + 1][1] : r1;
          int ks = t * 2 + kl;
          __builtin_amdgcn_s_setprio(1);
#pragma unroll
          for (int dt = 0; dt < 2; dt++) {
            bf16x8 vb = *(const bf16x8*)(vbase + (dt * 32 + lq) * 128 +
                                         ((ks * 32 + hi * 16) ^ lswz));
            acc[dt] = __builtin_amdgcn_mfma_f32_32x32x16_bf16(vb, pa.v, acc[dt], 0, 0, 0);
          }
          __builtin_amdgcn_s_setprio(0);
        }
      }
    }

    if (kt + 1 < kt1) {
      *(uint4*)((char*)Ks[b ^ 1] + sd0) = kr0;
      *(uint4*)((char*)Ks[b ^ 1] + sd1) = kr1;
      *(uint4*)((char*)Vs[b ^ 1] + sd0) = vr0;
      *(uint4*)((char*)Vs[b ^ 1] + sd1) = vr1;
    }
    __syncthreads();
  }

  // epilogue: dump raw-lane-layout partial O (bf16 pairs) + (m,l), coalesced
  unsigned* op = Opart + (size_t)c * OCH + ((size_t)(b5 * 4 + w) * 16) * 64;
#pragma unroll
  for (int dt = 0; dt < 2; dt++)
#pragma unroll
    for (int j = 0; j < 8; j++)
      op[(dt * 8 + j) * 64 + l] = pk2(acc[dt][2 * j], acc[dt][2 * j + 1]);
  if (!hi)
    ml[c * (HEADS * SEQ) + h * SEQ + wq0 + lq] = make_float2(m_r, l_r);
}

// ---------- Flash pass 2: merge chunk partials, transpose, write av ----------
__global__ __launch_bounds__(256) void k_merge(const unsigned* __restrict__ Opart,
                                               const float2* __restrict__ ml,
                                               u16* __restrict__ av) {
  __shared__ u16 Ts[8192];  // 16KB: 4 waves x 4KB transpose staging
  int bid = blockIdx.x;
  int h = bid & 31, qblk = bid >> 5;
  int b5 = ((SEQ / 128 - 1 - qblk) << 5) | h;  // pass-1 flat block index
  int tid = threadIdx.x, w = tid >> 6, l = tid & 63;
  int lq = l & 31, hi = l >> 5;
  int wq0 = qblk * 128 + w * 32;

  float2 ml0 = ml[h * SEQ + wq0 + lq];
  float2 ml1 = ml[HEADS * SEQ + h * SEQ + wq0 + lq];
  float m = fmaxf(ml0.x, ml1.x);
  float f0 = __builtin_amdgcn_exp2f(ml0.x - m);
  float f1 = __builtin_amdgcn_exp2f(ml1.x - m);
  float inv = 1.0f / (ml0.y * f0 + ml1.y * f1);

  const unsigned* op0 = Opart + ((size_t)(b5 * 4 + w) * 16) * 64;
  const unsigned* op1 = op0 + OCH;
  f32x16 acc[2];
#pragma unroll
  for (int dt = 0; dt < 2; dt++)
#pragma unroll
    for (int j = 0; j < 8; j++) {
      unsigned a0 = op0[(dt * 8 + j) * 64 + l];
      unsigned a1 = op1[(dt * 8 + j) * 64 + l];
      acc[dt][2 * j] = bflo(a0) * f0 + bflo(a1) * f1;
      acc[dt][2 * j + 1] = bfhi(a0) * f0 + bfhi(a1) * f1;
    }

  // LDS transpose epilogue (identical to R6 flash)
  int lswz = (lq & 7) << 4;
  char* wbase = (char*)Ts + w * 4096;
#pragma unroll
  for (int dt = 0; dt < 2; dt++)
#pragma unroll
    for (int m4 = 0; m4 < 4; m4++) {
      int r0 = 4 * m4;
      uint2 pr;
      pr.x = pk2(acc[dt][r0 + 0] * inv, acc[dt][r0 + 1] * inv);
      pr.y = pk2(acc[dt][r0 + 2] * inv, acc[dt][r0 + 3] * inv);
      int byte = lq * 128 + ((dt * 64 + m4 * 16 + hi * 8) ^ lswz);
      *(uint2*)(wbase + byte) = pr;
    }
  __syncthreads();
  int q2 = l >> 1, cH = l & 1;
  int qswz = (q2 & 7) << 4;
#pragma unroll
  for (int i = 0; i < 4; i++) {
    uint4 d = *(const uint4*)(wbase + q2 * 128 + ((cH * 64 + i * 16) ^ qswz));
    *(uint4*)(av + (size_t)(wq0 + q2) * HID + h * HD + cH * 32 + i * 8) = d;
  }
}

extern "C" void kernel_launch(void* const* d_in, const int* in_sizes, int n_in,
                              void* d_out, int out_size, void* d_ws, size_t ws_size,
                              hipStream_t stream) {
  (void)in_sizes; (void)n_in; (void)out_size; (void)ws_size;
  const float* x = (const float*)d_in[0];
  const float* cosp = (const float*)d_in[1];
  const float* sinp = (const float*)d_in[2];
  const float* Wq = (const float*)d_in[3];
  const float* Wk = (const float*)d_in[4];
  const float* Wv = (const float*)d_in[5];
  const float* Wo = (const float*)d_in[6];
  float* out = (float*)d_out;
  char* ws = (char*)d_ws;

  // workspace layout (64 MiB exactly):
  u16* xb = (u16*)(ws);                          // [0,8M)   x bf16; dead after qkv
  float2* mlb = (float2*)(ws);                   // [0,1M)   aliases dead xb (flash2+)
  u16* Wqkv = (u16*)(ws + ((size_t)8 << 20));    // [8,20M)  Wq^T|Wk^T|Wv^T
  u16* WoT = (u16*)(ws + ((size_t)20 << 20));    // [20,28M) Wo^T
  u16* qbuf = (u16*)(ws + ((size_t)28 << 20));   // [28,36M) q rope bf16 [32][S][64]
  u16* kbuf = (u16*)(ws + ((size_t)36 << 20));   // [36,38M) k rope bf16 [8][S][64]
  u16* vtb = (u16*)(ws + ((size_t)38 << 20));    // [38,40M) v^T bf16 [8][64][S]
  u16* av = (u16*)(ws + ((size_t)40 << 20));     // [40,48M) av bf16 [S][2048]
  unsigned* Opart = (unsigned*)(ws + ((size_t)48 << 20));  // [48,64M) 2 chunks x 8M

  k_f2b<<<(SEQ * HID / 4 + 255) / 256, 256, 0, stream>>>(x, xb, SEQ * HID / 4);
  k_tconv<<<dim3(HID / 32, HID / 32), 256, 0, stream>>>(Wq, HID, Wqkv, HID);
  k_tconv<<<dim3(512 / 32, HID / 32), 256, 0, stream>>>(Wk, 512, Wqkv + (size_t)2048 * HID, HID);
  k_tconv<<<dim3(512 / 32, HID / 32), 256, 0, stream>>>(Wv, 512, Wqkv + (size_t)2560 * HID, HID);
  k_tconv<<<dim3(HID / 32, HID / 32), 256, 0, stream>>>(Wo, HID, WoT, HID);
  k_gemm_qkv<<<384, 256, 0, stream>>>(xb, Wqkv, cosp, sinp, qbuf, kbuf, vtb);
  k_flash2<<<(SEQ / 128) * HEADS * 2, 256, 0, stream>>>(qbuf, kbuf, vtb, Opart, mlb);
  k_merge<<<(SEQ / 128) * HEADS, 256, 0, stream>>>(Opart, mlb, av);
  k_gemm<<<256, 256, 0, stream>>>(av, WoT, out, SEQ, HID, HID);
}

// Round 9
// 124.056 us; speedup vs baseline: 1.3205x; 1.0413x over previous
//
#include <hip/hip_runtime.h>

typedef unsigned short u16;
typedef __attribute__((ext_vector_type(4))) float f32x4;
typedef __attribute__((ext_vector_type(16))) float f32x16;
typedef __attribute__((ext_vector_type(8))) __bf16 bf16x8;
typedef __attribute__((ext_vector_type(2))) __bf16 bf16x2;

#define HEADS 32
#define KV_HEADS 8
#define HD 64
#define SEQ 2048
#define HID 2048
#define NQK 3072  // 2048 (Q) + 512 (K) + 512 (V)
#define QSCALE (0.125f * 1.4426950408889634f)  // exp2-domain softmax
#define OCH 2097152u  // u32s per partial-O chunk (512 blk * 4 waves * 16 * 64)

#define AS1 __attribute__((address_space(1)))
#define AS3 __attribute__((address_space(3)))

__device__ __forceinline__ u16 f2bf(float f) {
  unsigned u = __float_as_uint(f);
  u += 0x7FFFu + ((u >> 16) & 1u);
  return (u16)(u >> 16);
}

__device__ __forceinline__ unsigned pk2(float a, float b) {
  union { bf16x2 h; unsigned u; } c;
  c.h[0] = (__bf16)a; c.h[1] = (__bf16)b;
  return c.u;
}

__device__ __forceinline__ float bflo(unsigned u) {
  return __uint_as_float(u << 16);
}
__device__ __forceinline__ float bfhi(unsigned u) {
  return __uint_as_float(u & 0xFFFF0000u);
}

__device__ __forceinline__ void load16_to_lds(const void* g, void* l) {
  __builtin_amdgcn_global_load_lds((AS1 void*)(void*)g, (AS3 void*)l, 16, 0, 0);
}

// ---------- fp32 -> bf16 elementwise (4 elems/thread) ----------
__global__ __launch_bounds__(256) void k_f2b(const float* __restrict__ in,
                                             u16* __restrict__ out, int n4) {
  int i = blockIdx.x * 256 + threadIdx.x;
  if (i >= n4) return;
  float4 v = ((const float4*)in)[i];
  ushort4 o;
  o.x = f2bf(v.x); o.y = f2bf(v.y); o.z = f2bf(v.z); o.w = f2bf(v.w);
  ((ushort4*)out)[i] = o;
}

// ---------- transpose + convert: out[c*ldo + r] = bf16(in[r*ldi + c]) ----------
__global__ __launch_bounds__(256) void k_tconv(const float* __restrict__ in, int ldi,
                                               u16* __restrict__ out, int ldo) {
  __shared__ float tile[32][33];
  int c0 = blockIdx.x * 32, r0 = blockIdx.y * 32;
  int col = threadIdx.x & 31, rw = threadIdx.x >> 5;
#pragma unroll
  for (int i = 0; i < 4; i++)
    tile[rw + i * 8][col] = in[(size_t)(r0 + rw + i * 8) * ldi + c0 + col];
  __syncthreads();
#pragma unroll
  for (int i = 0; i < 4; i++)
    out[(size_t)(c0 + rw + i * 8) * ldo + r0 + col] = f2bf(tile[col][rw + i * 8]);
}

// ======================= out-proj GEMM (R3 template, verbatim) ==============
// 128x128 block tile, BK=64, 4 waves each 64x64 quadrant, depth-2 counted
// vmcnt pipeline, 8-slot source-swizzle.  2D grid 16x16 (best-total config).

__device__ __forceinline__ void stage8(const u16* Ap, const u16* Bp, u16* AsX,
                                       u16* BsX, int tid, int K, int koff) {
#pragma unroll
  for (int i = 0; i < 4; i++) {
    load16_to_lds(Ap + (size_t)(i * 32) * K + koff, AsX + (i * 256 + tid) * 8);
    load16_to_lds(Bp + (size_t)(i * 32) * K + koff, BsX + (i * 256 + tid) * 8);
  }
}

__device__ __forceinline__ void frag16(const u16* Asb, const u16* Bsb,
                                       const int aoff[4][2], const int boff[4][2],
                                       f32x4 acc[4][4]) {
#pragma unroll
  for (int kk = 0; kk < 2; kk++) {
    bf16x8 a[4], b[4];
#pragma unroll
    for (int i = 0; i < 4; i++)
      a[i] = *(const bf16x8*)((const char*)Asb + aoff[i][kk]);
#pragma unroll
    for (int j = 0; j < 4; j++)
      b[j] = *(const bf16x8*)((const char*)Bsb + boff[j][kk]);
#pragma unroll
    for (int i = 0; i < 4; i++)
#pragma unroll
      for (int j = 0; j < 4; j++)
        acc[i][j] = __builtin_amdgcn_mfma_f32_16x16x32_bf16(a[i], b[j], acc[i][j], 0, 0, 0);
  }
}

#define TILE_STEP(AsX, BsX, tnext)                              \
  do {                                                          \
    asm volatile("s_waitcnt vmcnt(8)" ::: "memory");            \
    __builtin_amdgcn_sched_barrier(0);                          \
    __builtin_amdgcn_s_barrier();                               \
    frag16(AsX, BsX, aoff, boff, acc);                          \
    __builtin_amdgcn_sched_barrier(0);                          \
    __builtin_amdgcn_s_barrier();                               \
    stage8(Ap, Bp, AsX, BsX, tid, K, (tnext) * 64);             \
    __builtin_amdgcn_sched_barrier(0);                          \
  } while (0)

#define TILE_TAIL(AsX, BsX, n)                                  \
  do {                                                          \
    asm volatile("s_waitcnt vmcnt(" #n ")" ::: "memory");       \
    __builtin_amdgcn_sched_barrier(0);                          \
    __builtin_amdgcn_s_barrier();                               \
    frag16(AsX, BsX, aoff, boff, acc);                          \
  } while (0)

__global__ __launch_bounds__(256) void k_gemm(const u16* __restrict__ A,
                                              const u16* __restrict__ Bt,
                                              float* __restrict__ C,
                                              int M, int N, int K) {
  __shared__ u16 smem[32768];  // 64KB: 2 x (A 16KB + B 16KB)
  u16* As0 = smem;          u16* As1 = smem + 8192;
  u16* Bs0 = smem + 16384;  u16* Bs1 = smem + 24576;
  int tid = threadIdx.x;
  int m0 = blockIdx.x * 128, n0 = blockIdx.y * 128;
  int l = tid & 63, w = tid >> 6;
  int lr = l & 15, lg = l >> 4;
  int wr = (w >> 1) * 64, wc = (w & 1) * 64;
  f32x4 acc[4][4] = {};
  int r8 = tid >> 3;
  int sx = (tid & 7) ^ (r8 & 7);
  const u16* Ap = A + (size_t)(m0 + r8) * K + sx * 8;
  const u16* Bp = Bt + (size_t)(n0 + r8) * K + sx * 8;
  int aoff[4][2], boff[4][2];
#pragma unroll
  for (int i = 0; i < 4; i++) {
    int ra = wr + i * 16 + lr;
    int rb = wc + i * 16 + lr;
#pragma unroll
    for (int kk = 0; kk < 2; kk++) {
      aoff[i][kk] = ra * 128 + (((lg + kk * 4) ^ (ra & 7)) << 4);
      boff[i][kk] = rb * 128 + (((lg + kk * 4) ^ (rb & 7)) << 4);
    }
  }
  stage8(Ap, Bp, As0, Bs0, tid, K, 0);
  stage8(Ap, Bp, As1, Bs1, tid, K, 64);
#pragma unroll 1
  for (int t = 0; t < 30; t += 2) {
    TILE_STEP(As0, Bs0, t + 2);
    TILE_STEP(As1, Bs1, t + 3);
  }
  TILE_TAIL(As0, Bs0, 8);
  TILE_TAIL(As1, Bs1, 0);

#pragma unroll
  for (int i = 0; i < 4; i++)
#pragma unroll
    for (int j = 0; j < 4; j++)
#pragma unroll
      for (int r = 0; r < 4; r++)
        C[(size_t)(m0 + wr + i * 16 + lg * 4 + r) * N + n0 + wc + j * 16 + lr] =
            acc[i][j][r];
}

// ======================= QKV GEMM (R9: 64x192 tile, grid 512 = 2/CU) ========
// R8 retile + bugfix: V-transpose drain restored to TWO passes (192 cols x 2
// halves = 384 work items > 256 threads; R8's single pass dropped cols
// 128..191 -> absmax 1.97).  Balanced grid (32x16 = 512 = exactly 2
// blocks/CU) AND 2-block TLP (64KB LDS/block).  Same R3 pipeline: depth-2,
// global_load_lds, 8-slot source-swizzle (i*32 = 0 mod 8 keeps the
// per-thread XOR identical across sub-loads), vmcnt(8) counted waits.
// Wave tile 32x96 (2x6 frags, 24 MFMA/tile).  XCD swizzle: 512 = 8 x 64;
// each XCD owns 2 contiguous B-panels (1.5MB L2-resident) + streams A.
// Epilogue: per-16-col-fragment Q/K/V classification (R6-validated).

__device__ __forceinline__ void stageQ(const u16* Ap, const u16* Bp, u16* S,
                                       int tid, int koff) {
#pragma unroll
  for (int i = 0; i < 2; i++)
    load16_to_lds(Ap + (size_t)(i * 32) * HID + koff, S + (i * 256 + tid) * 8);
#pragma unroll
  for (int i = 0; i < 6; i++)
    load16_to_lds(Bp + (size_t)(i * 32) * HID + koff, S + 4096 + (i * 256 + tid) * 8);
}

__device__ __forceinline__ void frag26(const u16* Sb, const int aoff[2][2],
                                       const int boff[6][2], f32x4 acc[2][6]) {
#pragma unroll
  for (int kk = 0; kk < 2; kk++) {
    bf16x8 a[2], b[6];
#pragma unroll
    for (int i = 0; i < 2; i++)
      a[i] = *(const bf16x8*)((const char*)Sb + aoff[i][kk]);
#pragma unroll
    for (int j = 0; j < 6; j++)
      b[j] = *(const bf16x8*)((const char*)Sb + 8192 + boff[j][kk]);
    __builtin_amdgcn_s_setprio(1);
#pragma unroll
    for (int i = 0; i < 2; i++)
#pragma unroll
      for (int j = 0; j < 6; j++)
        acc[i][j] = __builtin_amdgcn_mfma_f32_16x16x32_bf16(a[i], b[j], acc[i][j], 0, 0, 0);
    __builtin_amdgcn_s_setprio(0);
  }
}

#define QK_STEP(Sc, tnext)                                      \
  do {                                                          \
    asm volatile("s_waitcnt vmcnt(8)" ::: "memory");            \
    __builtin_amdgcn_sched_barrier(0);                          \
    __builtin_amdgcn_s_barrier();                               \
    frag26(Sc, aoff, boff, acc);                                \
    __builtin_amdgcn_sched_barrier(0);                          \
    __builtin_amdgcn_s_barrier();                               \
    stageQ(Ap, Bp, Sc, tid, (tnext) * 64);                      \
    __builtin_amdgcn_sched_barrier(0);                          \
  } while (0)

#define QK_TAIL(Sc, n)                                          \
  do {                                                          \
    asm volatile("s_waitcnt vmcnt(" #n ")" ::: "memory");       \
    __builtin_amdgcn_sched_barrier(0);                          \
    __builtin_amdgcn_s_barrier();                               \
    frag26(Sc, aoff, boff, acc);                                \
  } while (0)

__global__ __launch_bounds__(256) void k_gemm_qkv(const u16* __restrict__ A,
                                                  const u16* __restrict__ Bt,
                                                  const float* __restrict__ cosp,
                                                  const float* __restrict__ sinp,
                                                  u16* __restrict__ qbuf,
                                                  u16* __restrict__ kbuf,
                                                  u16* __restrict__ vtb) {
  __shared__ u16 smem[32768];  // 64KB: 2 sets x (A 8KB + B 24KB)
  u16* S0 = smem;              // set 0
  u16* S1 = smem + 16384;      // set 1
  u16* Ts = smem;              // 24KB: 192 cols x 64 rows x 2B (V epilogue)
  int tid = threadIdx.x;
  // XCD swizzle: grid 512 (32m x 16n); XCD (= bid%8 heuristic) owns 2 B-panels
  int bid = blockIdx.x;
  int wg = (bid & 7) * 64 + (bid >> 3);
  int m0 = (wg & 31) * 64, n0 = (wg >> 5) * 192;
  int l = tid & 63, w = tid >> 6;
  int lr = l & 15, lg = l >> 4;
  int wr = (w >> 1) * 32, wc = (w & 1) * 96;
  f32x4 acc[2][6] = {};
  int r8 = tid >> 3;
  int sx = (tid & 7) ^ (r8 & 7);
  const u16* Ap = A + (size_t)(m0 + r8) * HID + sx * 8;
  const u16* Bp = Bt + (size_t)(n0 + r8) * HID + sx * 8;
  int aoff[2][2], boff[6][2];
#pragma unroll
  for (int i = 0; i < 2; i++) {
    int ra = wr + i * 16 + lr;
#pragma unroll
    for (int kk = 0; kk < 2; kk++)
      aoff[i][kk] = ra * 128 + (((lg + kk * 4) ^ (ra & 7)) << 4);
  }
#pragma unroll
  for (int j = 0; j < 6; j++) {
    int rb = wc + j * 16 + lr;
#pragma unroll
    for (int kk = 0; kk < 2; kk++)
      boff[j][kk] = rb * 128 + (((lg + kk * 4) ^ (rb & 7)) << 4);
  }

  stageQ(Ap, Bp, S0, tid, 0);
  stageQ(Ap, Bp, S1, tid, 64);
#pragma unroll 1
  for (int t = 0; t < 30; t += 2) {
    QK_STEP(S0, t + 2);
    QK_STEP(S1, t + 3);
  }
  QK_TAIL(S0, 8);
  QK_TAIL(S1, 0);

  // ---- epilogue: per-fragment Q/K RoPE stores; V via Ts transpose ----
  int odd = lr & 1;
#pragma unroll
  for (int j = 0; j < 6; j++) {
    int colf = n0 + wc + j * 16;  // wave-uniform, multiple of 16
    if (colf < 2560) {
      bool isQ = colf < 2048;
      float scale = isQ ? QSCALE : 1.0f;
      u16* base = isQ ? qbuf + (size_t)(colf >> 6) * SEQ * HD
                      : kbuf + (size_t)((colf - 2048) >> 6) * SEQ * HD;
      int ch = colf & 63;              // col-in-head base (multiple of 16)
      int ii = (ch >> 1) + (lr >> 1);  // RoPE pair index within head
#pragma unroll
      for (int i = 0; i < 2; i++)
#pragma unroll
        for (int r = 0; r < 4; r++) {
          float v = acc[i][j][r];
          float vp = __shfl_xor(v, 1, 64);
          int sr = m0 + wr + i * 16 + lg * 4 + r;
          float cs = cosp[sr * 32 + ii], sn = sinp[sr * 32 + ii];
          float x1 = odd ? vp : v, x2 = odd ? v : vp;
          float o = odd ? (x1 * sn + x2 * cs) : (x1 * cs - x2 * sn);
          base[(size_t)sr * HD + ch + lr] = f2bf(o * scale);
        }
    }
  }
  if (n0 + 192 > 2560) {  // block contains V columns
    __syncthreads();      // all waves done with pipeline LDS
#pragma unroll
    for (int j = 0; j < 6; j++) {
      int colf = n0 + wc + j * 16;
      if (colf >= 2560) {
#pragma unroll
        for (int i = 0; i < 2; i++)
#pragma unroll
          for (int r = 0; r < 4; r++) {
            int cB = wc + j * 16 + lr, rB = wr + i * 16 + lg * 4 + r;
            *(u16*)((char*)Ts + cB * 128 + ((rB * 2) ^ ((cB & 7) << 4))) =
                f2bf(acc[i][j][r]);
          }
      }
    }
    __syncthreads();
    int half = tid & 1;
#pragma unroll
    for (int p = 0; p < 2; p++) {
      int c = p * 128 + (tid >> 1);
      if (c < 192 && n0 + c >= 2560) {
        int col = n0 + c;
        int kvh = (col - 2560) >> 6, d = col & 63;
        u16* dst = vtb + (size_t)kvh * HD * SEQ + (size_t)d * SEQ + m0 + half * 32;
        const char* src = (const char*)Ts + c * 128;
        int cs7 = (c & 7) << 4;
#pragma unroll
        for (int q = 0; q < 4; q++)
          *(uint4*)(dst + q * 8) = *(const uint4*)(src + ((half * 64 + q * 16) ^ cs7));
      }
    }
  }
}

// ---------- Flash attention pass 1: KV-split x2, partial O + (m,l) ----------
__global__ __launch_bounds__(256) void k_flash2(const u16* __restrict__ qb,
                                                const u16* __restrict__ kb,
                                                const u16* __restrict__ vt,
                                                unsigned* __restrict__ Opart,
                                                float2* __restrict__ ml) {
  __shared__ u16 Ks[2][64 * 64];
  __shared__ u16 Vs[2][64 * 64];
  int bid = blockIdx.x;
  int c = bid & 1;                  // chunk fastest
  int b5 = bid >> 1;                // 0..511
  int h = b5 & 31;                  // heads next
  int qi = b5 >> 5;
  int qblk = (SEQ / 128) - 1 - qi;  // LPT: heaviest first
  int kvh = h & 7;
  int tid = threadIdx.x, w = tid >> 6, l = tid & 63;
  int lq = l & 31, hi = l >> 5;
  const u16* qh = qb + (size_t)h * SEQ * HD;
  const u16* kh = kb + (size_t)kvh * SEQ * HD;
  const u16* vh = vt + (size_t)kvh * HD * SEQ;
  int wq0 = qblk * 128 + w * 32;
  int qg = wq0 + lq;

  bf16x8 qf[4];
#pragma unroll
  for (int ds = 0; ds < 4; ds++)
    qf[ds] = *(const bf16x8*)(qh + (size_t)qg * HD + ds * 16 + hi * 8);

  f32x16 acc[2] = {};   // O^T: lane: q=l&31, d = dt*32 + (r&3)+8*(r>>2)+4*hi
  float m_r = -__builtin_inff(), l_r = 0.f;

  int srow = tid >> 2, c4 = tid & 3, swz = (srow & 7) << 4;
  int sd0 = srow * 128 + ((c4 * 32) ^ swz);
  int sd1 = srow * 128 + ((c4 * 32 + 16) ^ swz);
  const int kt0 = c * (qblk + 1), kt1 = kt0 + qblk + 1;

  // prologue: stage tile kt0
  {
    const u16* ksrc = kh + (size_t)(kt0 * 64 + srow) * HD + c4 * 16;
    const u16* vsrc = vh + (size_t)srow * SEQ + kt0 * 64 + c4 * 16;
    uint4 a0 = *(const uint4*)(ksrc), a1 = *(const uint4*)(ksrc + 8);
    uint4 b0 = *(const uint4*)(vsrc), b1 = *(const uint4*)(vsrc + 8);
    *(uint4*)((char*)Ks[0] + sd0) = a0; *(uint4*)((char*)Ks[0] + sd1) = a1;
    *(uint4*)((char*)Vs[0] + sd0) = b0; *(uint4*)((char*)Vs[0] + sd1) = b1;
  }
  __syncthreads();

  uint4 kr0, kr1, vr0, vr1;
  int lswz = (lq & 7) << 4;
  for (int kt = kt0; kt < kt1; kt++) {
    int b = (kt - kt0) & 1;
    if (kt + 1 < kt1) {
      const u16* ksrc = kh + (size_t)((kt + 1) * 64 + srow) * HD + c4 * 16;
      const u16* vsrc = vh + (size_t)srow * SEQ + (kt + 1) * 64 + c4 * 16;
      kr0 = *(const uint4*)(ksrc); kr1 = *(const uint4*)(ksrc + 8);
      vr0 = *(const uint4*)(vsrc); vr1 = *(const uint4*)(vsrc + 8);
    }

    if (kt * 64 <= wq0 + 31) {  // skip fully-masked tiles
      f32x16 sT[2] = {};
      const char* kbase = (const char*)Ks[b];
      __builtin_amdgcn_s_setprio(1);
#pragma unroll
      for (int t = 0; t < 2; t++) {
#pragma unroll
        for (int ds = 0; ds < 4; ds++) {
          bf16x8 kf = *(const bf16x8*)(kbase + (t * 32 + lq) * 128 +
                                       ((ds * 32 + hi * 16) ^ lswz));
          sT[t] = __builtin_amdgcn_mfma_f32_32x32x16_bf16(kf, qf[ds], sT[t], 0, 0, 0);
        }
      }
      __builtin_amdgcn_s_setprio(0);

      if (kt * 64 + 63 > wq0) {
#pragma unroll
        for (int t = 0; t < 2; t++)
#pragma unroll
          for (int r = 0; r < 16; r++) {
            int kg = kt * 64 + t * 32 + (r & 3) + 8 * (r >> 2) + 4 * hi;
            if (kg > qg) sT[t][r] = -__builtin_inff();
          }
      }

      float pmax = sT[0][0];
#pragma unroll
      for (int r = 1; r < 16; r++) pmax = fmaxf(pmax, sT[0][r]);
#pragma unroll
      for (int r = 0; r < 16; r++) pmax = fmaxf(pmax, sT[1][r]);
      pmax = fmaxf(pmax, __shfl_xor(pmax, 32, 64));

      if (!__all(pmax <= m_r + 8.f)) {
        float mn = fmaxf(m_r, pmax);
        float scl = __builtin_amdgcn_exp2f(m_r - mn);
        l_r *= scl;
        acc[0] *= scl;
        acc[1] *= scl;
        m_r = mn;
      }

      float ss = 0.f;
#pragma unroll
      for (int t = 0; t < 2; t++)
#pragma unroll
        for (int r = 0; r < 16; r++) {
          float p = __builtin_amdgcn_exp2f(sT[t][r] - m_r);
          sT[t][r] = p;
          ss += p;
        }
      ss += __shfl_xor(ss, 32, 64);
      l_r += ss;

      const char* vbase = (const char*)Vs[b];
#pragma unroll
      for (int t = 0; t < 2; t++) {
        unsigned cp[4][2];
#pragma unroll
        for (int m = 0; m < 4; m++) {
          cp[m][0] = pk2(sT[t][4 * m + 0], sT[t][4 * m + 1]);
          cp[m][1] = pk2(sT[t][4 * m + 2], sT[t][4 * m + 3]);
        }
#pragma unroll
        for (int kl = 0; kl < 2; kl++) {
          unsigned s0 = hi ? cp[2 * kl][0] : cp[2 * kl + 1][0];
          unsigned s1 = hi ? cp[2 * kl][1] : cp[2 * kl + 1][1];
          unsigned r0 = (unsigned)__shfl_xor((int)s0, 32, 64);
          unsigned r1 = (unsigned)__shfl_xor((int)s1, 32, 64);
          union { unsigned u[4]; bf16x8 v; } pa;
          pa.u[0] = hi ? r0 : cp[2 * kl][0];
          pa.u[1] = hi ? r1 : cp[2 * kl][1];
          pa.u[2] = hi ? cp[2 * kl + 1][0] : r0;
          pa.u[3] = hi ? cp[2 * kl + 1][1] : r1;
          int ks = t * 2 + kl;
          __builtin_amdgcn_s_setprio(1);
#pragma unroll
          for (int dt = 0; dt < 2; dt++) {
            bf16x8 vb = *(const bf16x8*)(vbase + (dt * 32 + lq) * 128 +
                                         ((ks * 32 + hi * 16) ^ lswz));
            acc[dt] = __builtin_amdgcn_mfma_f32_32x32x16_bf16(vb, pa.v, acc[dt], 0, 0, 0);
          }
          __builtin_amdgcn_s_setprio(0);
        }
      }
    }

    if (kt + 1 < kt1) {
      *(uint4*)((char*)Ks[b ^ 1] + sd0) = kr0;
      *(uint4*)((char*)Ks[b ^ 1] + sd1) = kr1;
      *(uint4*)((char*)Vs[b ^ 1] + sd0) = vr0;
      *(uint4*)((char*)Vs[b ^ 1] + sd1) = vr1;
    }
    __syncthreads();
  }

  // epilogue: dump raw-lane-layout partial O (bf16 pairs) + (m,l), coalesced
  unsigned* op = Opart + (size_t)c * OCH + ((size_t)(b5 * 4 + w) * 16) * 64;
#pragma unroll
  for (int dt = 0; dt < 2; dt++)
#pragma unroll
    for (int j = 0; j < 8; j++)
      op[(dt * 8 + j) * 64 + l] = pk2(acc[dt][2 * j], acc[dt][2 * j + 1]);
  if (!hi)
    ml[c * (HEADS * SEQ) + h * SEQ + wq0 + lq] = make_float2(m_r, l_r);
}

// ---------- Flash pass 2: merge chunk partials, transpose, write av ----------
__global__ __launch_bounds__(256) void k_merge(const unsigned* __restrict__ Opart,
                                               const float2* __restrict__ ml,
                                               u16* __restrict__ av) {
  __shared__ u16 Ts[8192];  // 16KB: 4 waves x 4KB transpose staging
  int bid = blockIdx.x;
  int h = bid & 31, qblk = bid >> 5;
  int b5 = ((SEQ / 128 - 1 - qblk) << 5) | h;  // pass-1 flat block index
  int tid = threadIdx.x, w = tid >> 6, l = tid & 63;
  int lq = l & 31, hi = l >> 5;
  int wq0 = qblk * 128 + w * 32;

  float2 ml0 = ml[h * SEQ + wq0 + lq];
  float2 ml1 = ml[HEADS * SEQ + h * SEQ + wq0 + lq];
  float m = fmaxf(ml0.x, ml1.x);
  float f0 = __builtin_amdgcn_exp2f(ml0.x - m);
  float f1 = __builtin_amdgcn_exp2f(ml1.x - m);
  float inv = 1.0f / (ml0.y * f0 + ml1.y * f1);

  const unsigned* op0 = Opart + ((size_t)(b5 * 4 + w) * 16) * 64;
  const unsigned* op1 = op0 + OCH;
  f32x16 acc[2];
#pragma unroll
  for (int dt = 0; dt < 2; dt++)
#pragma unroll
    for (int j = 0; j < 8; j++) {
      unsigned a0 = op0[(dt * 8 + j) * 64 + l];
      unsigned a1 = op1[(dt * 8 + j) * 64 + l];
      acc[dt][2 * j] = bflo(a0) * f0 + bflo(a1) * f1;
      acc[dt][2 * j + 1] = bfhi(a0) * f0 + bfhi(a1) * f1;
    }

  // LDS transpose epilogue (identical to R6 flash)
  int lswz = (lq & 7) << 4;
  char* wbase = (char*)Ts + w * 4096;
#pragma unroll
  for (int dt = 0; dt < 2; dt++)
#pragma unroll
    for (int m4 = 0; m4 < 4; m4++) {
      int r0 = 4 * m4;
      uint2 pr;
      pr.x = pk2(acc[dt][r0 + 0] * inv, acc[dt][r0 + 1] * inv);
      pr.y = pk2(acc[dt][r0 + 2] * inv, acc[dt][r0 + 3] * inv);
      int byte = lq * 128 + ((dt * 64 + m4 * 16 + hi * 8) ^ lswz);
      *(uint2*)(wbase + byte) = pr;
    }
  __syncthreads();
  int q2 = l >> 1, cH = l & 1;
  int qswz = (q2 & 7) << 4;
#pragma unroll
  for (int i = 0; i < 4; i++) {
    uint4 d = *(const uint4*)(wbase + q2 * 128 + ((cH * 64 + i * 16) ^ qswz));
    *(uint4*)(av + (size_t)(wq0 + q2) * HID + h * HD + cH * 32 + i * 8) = d;
  }
}

extern "C" void kernel_launch(void* const* d_in, const int* in_sizes, int n_in,
                              void* d_out, int out_size, void* d_ws, size_t ws_size,
                              hipStream_t stream) {
  (void)in_sizes; (void)n_in; (void)out_size; (void)ws_size;
  const float* x = (const float*)d_in[0];
  const float* cosp = (const float*)d_in[1];
  const float* sinp = (const float*)d_in[2];
  const float* Wq = (const float*)d_in[3];
  const float* Wk = (const float*)d_in[4];
  const float* Wv = (const float*)d_in[5];
  const float* Wo = (const float*)d_in[6];
  float* out = (float*)d_out;
  char* ws = (char*)d_ws;

  // workspace layout (64 MiB exactly):
  u16* xb = (u16*)(ws);                          // [0,8M)   x bf16; dead after qkv
  float2* mlb = (float2*)(ws);                   // [0,1M)   aliases dead xb (flash2+)
  u16* Wqkv = (u16*)(ws + ((size_t)8 << 20));    // [8,20M)  Wq^T|Wk^T|Wv^T
  u16* WoT = (u16*)(ws + ((size_t)20 << 20));    // [20,28M) Wo^T
  u16* qbuf = (u16*)(ws + ((size_t)28 << 20));   // [28,36M) q rope bf16 [32][S][64]
  u16* kbuf = (u16*)(ws + ((size_t)36 << 20));   // [36,38M) k rope bf16 [8][S][64]
  u16* vtb = (u16*)(ws + ((size_t)38 << 20));    // [38,40M) v^T bf16 [8][64][S]
  u16* av = (u16*)(ws + ((size_t)40 << 20));     // [40,48M) av bf16 [S][2048]
  unsigned* Opart = (unsigned*)(ws + ((size_t)48 << 20));  // [48,64M) 2 chunks x 8M

  k_f2b<<<(SEQ * HID / 4 + 255) / 256, 256, 0, stream>>>(x, xb, SEQ * HID / 4);
  k_tconv<<<dim3(HID / 32, HID / 32), 256, 0, stream>>>(Wq, HID, Wqkv, HID);
  k_tconv<<<dim3(512 / 32, HID / 32), 256, 0, stream>>>(Wk, 512, Wqkv + (size_t)2048 * HID, HID);
  k_tconv<<<dim3(512 / 32, HID / 32), 256, 0, stream>>>(Wv, 512, Wqkv + (size_t)2560 * HID, HID);
  k_tconv<<<dim3(HID / 32, HID / 32), 256, 0, stream>>>(Wo, HID, WoT, HID);
  k_gemm_qkv<<<512, 256, 0, stream>>>(xb, Wqkv, cosp, sinp, qbuf, kbuf, vtb);
  k_flash2<<<(SEQ / 128) * HEADS * 2, 256, 0, stream>>>(qbuf, kbuf, vtb, Opart, mlb);
  k_merge<<<(SEQ / 128) * HEADS, 256, 0, stream>>>(Opart, mlb, av);
  k_gemm<<<dim3(SEQ / 128, HID / 128), 256, 0, stream>>>(av, WoT, out, SEQ, HID, HID);
}

// Round 10
// 120.943 us; speedup vs baseline: 1.3545x; 1.0257x over previous
//
#include <hip/hip_runtime.h>

typedef unsigned short u16;
typedef __attribute__((ext_vector_type(4))) float f32x4;
typedef __attribute__((ext_vector_type(16))) float f32x16;
typedef __attribute__((ext_vector_type(8))) __bf16 bf16x8;
typedef __attribute__((ext_vector_type(2))) __bf16 bf16x2;

#define HEADS 32
#define KV_HEADS 8
#define HD 64
#define SEQ 2048
#define HID 2048
#define NQK 3072  // 2048 (Q) + 512 (K) + 512 (V)
#define QSCALE (0.125f * 1.4426950408889634f)  // exp2-domain softmax
#define OCH 2097152u  // u32s per partial-O chunk (512 blk * 4 waves * 16 * 64)

#define AS1 __attribute__((address_space(1)))
#define AS3 __attribute__((address_space(3)))

__device__ __forceinline__ u16 f2bf(float f) {
  unsigned u = __float_as_uint(f);
  u += 0x7FFFu + ((u >> 16) & 1u);
  return (u16)(u >> 16);
}

__device__ __forceinline__ unsigned pk2(float a, float b) {
  union { bf16x2 h; unsigned u; } c;
  c.h[0] = (__bf16)a; c.h[1] = (__bf16)b;
  return c.u;
}

__device__ __forceinline__ float bflo(unsigned u) {
  return __uint_as_float(u << 16);
}
__device__ __forceinline__ float bfhi(unsigned u) {
  return __uint_as_float(u & 0xFFFF0000u);
}

__device__ __forceinline__ void load16_to_lds(const void* g, void* l) {
  __builtin_amdgcn_global_load_lds((AS1 void*)(void*)g, (AS3 void*)l, 16, 0, 0);
}

// ---------- fp32 -> bf16 elementwise (4 elems/thread) ----------
__global__ __launch_bounds__(256) void k_f2b(const float* __restrict__ in,
                                             u16* __restrict__ out, int n4) {
  int i = blockIdx.x * 256 + threadIdx.x;
  if (i >= n4) return;
  float4 v = ((const float4*)in)[i];
  ushort4 o;
  o.x = f2bf(v.x); o.y = f2bf(v.y); o.z = f2bf(v.z); o.w = f2bf(v.w);
  ((ushort4*)out)[i] = o;
}

// ---------- fused transpose+convert for all 4 weight matrices ----------
// out[c*ldo + r] = bf16(in[r*ldi + c]); flat grid, range-decoded segments:
// [0,4096)      Wq  (2048x2048) -> Wqkv
// [4096,5120)   Wk  (2048x512)  -> Wqkv + 2048*2048
// [5120,6144)   Wv  (2048x512)  -> Wqkv + 2560*2048
// [6144,10240)  Wo  (2048x2048) -> WoT
__global__ __launch_bounds__(256) void k_tconv4(const float* __restrict__ Wq,
                                                const float* __restrict__ Wk,
                                                const float* __restrict__ Wv,
                                                const float* __restrict__ Wo,
                                                u16* __restrict__ Wqkv,
                                                u16* __restrict__ WoT) {
  __shared__ float tile[32][33];
  int bid = blockIdx.x;
  const float* in; u16* out; int ldi, cx, cy;
  if (bid < 4096) {
    in = Wq; out = Wqkv; ldi = 2048; cx = bid & 63; cy = bid >> 6;
  } else if (bid < 5120) {
    int b = bid - 4096;
    in = Wk; out = Wqkv + (size_t)2048 * 2048; ldi = 512; cx = b & 15; cy = b >> 4;
  } else if (bid < 6144) {
    int b = bid - 5120;
    in = Wv; out = Wqkv + (size_t)2560 * 2048; ldi = 512; cx = b & 15; cy = b >> 4;
  } else {
    int b = bid - 6144;
    in = Wo; out = WoT; ldi = 2048; cx = b & 63; cy = b >> 6;
  }
  const int ldo = 2048;
  int c0 = cx * 32, r0 = cy * 32;
  int col = threadIdx.x & 31, rw = threadIdx.x >> 5;
#pragma unroll
  for (int i = 0; i < 4; i++)
    tile[rw + i * 8][col] = in[(size_t)(r0 + rw + i * 8) * ldi + c0 + col];
  __syncthreads();
#pragma unroll
  for (int i = 0; i < 4; i++)
    out[(size_t)(c0 + rw + i * 8) * ldo + r0 + col] = f2bf(tile[col][rw + i * 8]);
}

// ======================= out-proj GEMM (R3 template, verbatim) ==============
// 128x128 block tile, BK=64, 4 waves each 64x64 quadrant, depth-2 counted
// vmcnt pipeline, 8-slot source-swizzle.  2D grid 16x16 (best-total config).

__device__ __forceinline__ void stage8(const u16* Ap, const u16* Bp, u16* AsX,
                                       u16* BsX, int tid, int K, int koff) {
#pragma unroll
  for (int i = 0; i < 4; i++) {
    load16_to_lds(Ap + (size_t)(i * 32) * K + koff, AsX + (i * 256 + tid) * 8);
    load16_to_lds(Bp + (size_t)(i * 32) * K + koff, BsX + (i * 256 + tid) * 8);
  }
}

__device__ __forceinline__ void frag16(const u16* Asb, const u16* Bsb,
                                       const int aoff[4][2], const int boff[4][2],
                                       f32x4 acc[4][4]) {
#pragma unroll
  for (int kk = 0; kk < 2; kk++) {
    bf16x8 a[4], b[4];
#pragma unroll
    for (int i = 0; i < 4; i++)
      a[i] = *(const bf16x8*)((const char*)Asb + aoff[i][kk]);
#pragma unroll
    for (int j = 0; j < 4; j++)
      b[j] = *(const bf16x8*)((const char*)Bsb + boff[j][kk]);
#pragma unroll
    for (int i = 0; i < 4; i++)
#pragma unroll
      for (int j = 0; j < 4; j++)
        acc[i][j] = __builtin_amdgcn_mfma_f32_16x16x32_bf16(a[i], b[j], acc[i][j], 0, 0, 0);
  }
}

#define TILE_STEP(AsX, BsX, tnext)                              \
  do {                                                          \
    asm volatile("s_waitcnt vmcnt(8)" ::: "memory");            \
    __builtin_amdgcn_sched_barrier(0);                          \
    __builtin_amdgcn_s_barrier();                               \
    frag16(AsX, BsX, aoff, boff, acc);                          \
    __builtin_amdgcn_sched_barrier(0);                          \
    __builtin_amdgcn_s_barrier();                               \
    stage8(Ap, Bp, AsX, BsX, tid, K, (tnext) * 64);             \
    __builtin_amdgcn_sched_barrier(0);                          \
  } while (0)

#define TILE_TAIL(AsX, BsX, n)                                  \
  do {                                                          \
    asm volatile("s_waitcnt vmcnt(" #n ")" ::: "memory");       \
    __builtin_amdgcn_sched_barrier(0);                          \
    __builtin_amdgcn_s_barrier();                               \
    frag16(AsX, BsX, aoff, boff, acc);                          \
  } while (0)

__global__ __launch_bounds__(256) void k_gemm(const u16* __restrict__ A,
                                              const u16* __restrict__ Bt,
                                              float* __restrict__ C,
                                              int M, int N, int K) {
  __shared__ u16 smem[32768];  // 64KB: 2 x (A 16KB + B 16KB)
  u16* As0 = smem;          u16* As1 = smem + 8192;
  u16* Bs0 = smem + 16384;  u16* Bs1 = smem + 24576;
  int tid = threadIdx.x;
  int m0 = blockIdx.x * 128, n0 = blockIdx.y * 128;
  int l = tid & 63, w = tid >> 6;
  int lr = l & 15, lg = l >> 4;
  int wr = (w >> 1) * 64, wc = (w & 1) * 64;
  f32x4 acc[4][4] = {};
  int r8 = tid >> 3;
  int sx = (tid & 7) ^ (r8 & 7);
  const u16* Ap = A + (size_t)(m0 + r8) * K + sx * 8;
  const u16* Bp = Bt + (size_t)(n0 + r8) * K + sx * 8;
  int aoff[4][2], boff[4][2];
#pragma unroll
  for (int i = 0; i < 4; i++) {
    int ra = wr + i * 16 + lr;
    int rb = wc + i * 16 + lr;
#pragma unroll
    for (int kk = 0; kk < 2; kk++) {
      aoff[i][kk] = ra * 128 + (((lg + kk * 4) ^ (ra & 7)) << 4);
      boff[i][kk] = rb * 128 + (((lg + kk * 4) ^ (rb & 7)) << 4);
    }
  }
  stage8(Ap, Bp, As0, Bs0, tid, K, 0);
  stage8(Ap, Bp, As1, Bs1, tid, K, 64);
#pragma unroll 1
  for (int t = 0; t < 30; t += 2) {
    TILE_STEP(As0, Bs0, t + 2);
    TILE_STEP(As1, Bs1, t + 3);
  }
  TILE_TAIL(As0, Bs0, 8);
  TILE_TAIL(As1, Bs1, 0);

#pragma unroll
  for (int i = 0; i < 4; i++)
#pragma unroll
    for (int j = 0; j < 4; j++)
#pragma unroll
      for (int r = 0; r < 4; r++)
        C[(size_t)(m0 + wr + i * 16 + lg * 4 + r) * N + n0 + wc + j * 16 + lr] =
            acc[i][j][r];
}

// ======================= QKV GEMM (R10: 64x384, 512 thr, 1 blk/CU) ==========
// 8 waves (2M x 4N, wave tile 32x96 = R9's) in ONE block, grid 256 = 1/CU:
// same waves/SIMD as R9 (2) but one barrier domain instead of two independent
// 4-wave blocks, 56KB (vs 64KB) staged per CU per tile, and perfect XCD
// locality (each XCD's 32 blocks share exactly ONE 1.5MB B-panel).
// Pipeline identical to R9: depth-2, global_load_lds, 8-slot source-swizzle,
// counted vmcnt(7) (7 loads/thread/tile: A 1 + B 6).  LDS 112KB (2 x 56KB).
// Epilogue: per-16-col-fragment Q/K/V classification; V drain 2 passes
// (384 cols x 2 halves = 768 items on 512 threads).

__device__ __forceinline__ void stageQ8(const u16* Ap, const u16* Bp, u16* S,
                                        int tid, int koff) {
  load16_to_lds(Ap + koff, S + tid * 8);
#pragma unroll
  for (int i = 0; i < 6; i++)
    load16_to_lds(Bp + (size_t)(i * 64) * HID + koff, S + 4096 + (i * 512 + tid) * 8);
}

__device__ __forceinline__ void frag26(const u16* Sb, const int aoff[2][2],
                                       const int boff[6][2], f32x4 acc[2][6]) {
#pragma unroll
  for (int kk = 0; kk < 2; kk++) {
    bf16x8 a[2], b[6];
#pragma unroll
    for (int i = 0; i < 2; i++)
      a[i] = *(const bf16x8*)((const char*)Sb + aoff[i][kk]);
#pragma unroll
    for (int j = 0; j < 6; j++)
      b[j] = *(const bf16x8*)((const char*)Sb + 8192 + boff[j][kk]);
    __builtin_amdgcn_s_setprio(1);
#pragma unroll
    for (int i = 0; i < 2; i++)
#pragma unroll
      for (int j = 0; j < 6; j++)
        acc[i][j] = __builtin_amdgcn_mfma_f32_16x16x32_bf16(a[i], b[j], acc[i][j], 0, 0, 0);
    __builtin_amdgcn_s_setprio(0);
  }
}

#define QK_STEP(Sc, tnext)                                      \
  do {                                                          \
    asm volatile("s_waitcnt vmcnt(7)" ::: "memory");            \
    __builtin_amdgcn_sched_barrier(0);                          \
    __builtin_amdgcn_s_barrier();                               \
    frag26(Sc, aoff, boff, acc);                                \
    __builtin_amdgcn_sched_barrier(0);                          \
    __builtin_amdgcn_s_barrier();                               \
    stageQ8(Ap, Bp, Sc, tid, (tnext) * 64);                     \
    __builtin_amdgcn_sched_barrier(0);                          \
  } while (0)

#define QK_TAIL(Sc, n)                                          \
  do {                                                          \
    asm volatile("s_waitcnt vmcnt(" #n ")" ::: "memory");       \
    __builtin_amdgcn_sched_barrier(0);                          \
    __builtin_amdgcn_s_barrier();                               \
    frag26(Sc, aoff, boff, acc);                                \
  } while (0)

__global__ __launch_bounds__(512, 2) void k_gemm_qkv(const u16* __restrict__ A,
                                                     const u16* __restrict__ Bt,
                                                     const float* __restrict__ cosp,
                                                     const float* __restrict__ sinp,
                                                     u16* __restrict__ qbuf,
                                                     u16* __restrict__ kbuf,
                                                     u16* __restrict__ vtb) {
  __shared__ u16 smem[57344];  // 112KB: 2 sets x (A 8KB + B 48KB)
  u16* S0 = smem;              // set 0
  u16* S1 = smem + 28672;      // set 1
  u16* Ts = smem;              // 48KB: 384 cols x 64 rows x 2B (V epilogue)
  int tid = threadIdx.x;
  // XCD swizzle: grid 256 (32m x 8n); XCD (= bid%8 heuristic) owns ONE B-panel
  int bid = blockIdx.x;
  int wg = (bid & 7) * 32 + (bid >> 3);
  int m0 = (wg & 31) * 64, n0 = (wg >> 5) * 384;
  int l = tid & 63, w = tid >> 6;
  int lr = l & 15, lg = l >> 4;
  int wr = (w >> 2) * 32, wc = (w & 3) * 96;
  f32x4 acc[2][6] = {};
  int r8 = tid >> 3;
  int sx = (tid & 7) ^ (r8 & 7);
  const u16* Ap = A + (size_t)(m0 + r8) * HID + sx * 8;
  const u16* Bp = Bt + (size_t)(n0 + r8) * HID + sx * 8;
  int aoff[2][2], boff[6][2];
#pragma unroll
  for (int i = 0; i < 2; i++) {
    int ra = wr + i * 16 + lr;
#pragma unroll
    for (int kk = 0; kk < 2; kk++)
      aoff[i][kk] = ra * 128 + (((lg + kk * 4) ^ (ra & 7)) << 4);
  }
#pragma unroll
  for (int j = 0; j < 6; j++) {
    int rb = wc + j * 16 + lr;
#pragma unroll
    for (int kk = 0; kk < 2; kk++)
      boff[j][kk] = rb * 128 + (((lg + kk * 4) ^ (rb & 7)) << 4);
  }

  stageQ8(Ap, Bp, S0, tid, 0);
  stageQ8(Ap, Bp, S1, tid, 64);
#pragma unroll 1
  for (int t = 0; t < 30; t += 2) {
    QK_STEP(S0, t + 2);
    QK_STEP(S1, t + 3);
  }
  QK_TAIL(S0, 7);
  QK_TAIL(S1, 0);

  // ---- epilogue: per-fragment Q/K RoPE stores; V via Ts transpose ----
  int odd = lr & 1;
#pragma unroll
  for (int j = 0; j < 6; j++) {
    int colf = n0 + wc + j * 16;  // wave-uniform, multiple of 16
    if (colf < 2560) {
      bool isQ = colf < 2048;
      float scale = isQ ? QSCALE : 1.0f;
      u16* base = isQ ? qbuf + (size_t)(colf >> 6) * SEQ * HD
                      : kbuf + (size_t)((colf - 2048) >> 6) * SEQ * HD;
      int ch = colf & 63;              // col-in-head base (multiple of 16)
      int ii = (ch >> 1) + (lr >> 1);  // RoPE pair index within head
#pragma unroll
      for (int i = 0; i < 2; i++)
#pragma unroll
        for (int r = 0; r < 4; r++) {
          float v = acc[i][j][r];
          float vp = __shfl_xor(v, 1, 64);
          int sr = m0 + wr + i * 16 + lg * 4 + r;
          float cs = cosp[sr * 32 + ii], sn = sinp[sr * 32 + ii];
          float x1 = odd ? vp : v, x2 = odd ? v : vp;
          float o = odd ? (x1 * sn + x2 * cs) : (x1 * cs - x2 * sn);
          base[(size_t)sr * HD + ch + lr] = f2bf(o * scale);
        }
    }
  }
  if (n0 + 384 > 2560) {  // block contains V columns
    __syncthreads();      // all waves done with pipeline LDS
#pragma unroll
    for (int j = 0; j < 6; j++) {
      int colf = n0 + wc + j * 16;
      if (colf >= 2560) {
#pragma unroll
        for (int i = 0; i < 2; i++)
#pragma unroll
          for (int r = 0; r < 4; r++) {
            int cB = wc + j * 16 + lr, rB = wr + i * 16 + lg * 4 + r;
            *(u16*)((char*)Ts + cB * 128 + ((rB * 2) ^ ((cB & 7) << 4))) =
                f2bf(acc[i][j][r]);
          }
      }
    }
    __syncthreads();
    int half = tid & 1;
#pragma unroll
    for (int p = 0; p < 2; p++) {
      int c = p * 256 + (tid >> 1);
      if (c < 384 && n0 + c >= 2560) {
        int col = n0 + c;
        int kvh = (col - 2560) >> 6, d = col & 63;
        u16* dst = vtb + (size_t)kvh * HD * SEQ + (size_t)d * SEQ + m0 + half * 32;
        const char* src = (const char*)Ts + c * 128;
        int cs7 = (c & 7) << 4;
#pragma unroll
        for (int q = 0; q < 4; q++)
          *(uint4*)(dst + q * 8) = *(const uint4*)(src + ((half * 64 + q * 16) ^ cs7));
      }
    }
  }
}

// ---------- Flash attention pass 1: KV-split x2, partial O + (m,l) ----------
__global__ __launch_bounds__(256) void k_flash2(const u16* __restrict__ qb,
                                                const u16* __restrict__ kb,
                                                const u16* __restrict__ vt,
                                                unsigned* __restrict__ Opart,
                                                float2* __restrict__ ml) {
  __shared__ u16 Ks[2][64 * 64];
  __shared__ u16 Vs[2][64 * 64];
  int bid = blockIdx.x;
  int c = bid & 1;                  // chunk fastest
  int b5 = bid >> 1;                // 0..511
  int h = b5 & 31;                  // heads next
  int qi = b5 >> 5;
  int qblk = (SEQ / 128) - 1 - qi;  // LPT: heaviest first
  int kvh = h & 7;
  int tid = threadIdx.x, w = tid >> 6, l = tid & 63;
  int lq = l & 31, hi = l >> 5;
  const u16* qh = qb + (size_t)h * SEQ * HD;
  const u16* kh = kb + (size_t)kvh * SEQ * HD;
  const u16* vh = vt + (size_t)kvh * HD * SEQ;
  int wq0 = qblk * 128 + w * 32;
  int qg = wq0 + lq;

  bf16x8 qf[4];
#pragma unroll
  for (int ds = 0; ds < 4; ds++)
    qf[ds] = *(const bf16x8*)(qh + (size_t)qg * HD + ds * 16 + hi * 8);

  f32x16 acc[2] = {};   // O^T: lane: q=l&31, d = dt*32 + (r&3)+8*(r>>2)+4*hi
  float m_r = -__builtin_inff(), l_r = 0.f;

  int srow = tid >> 2, c4 = tid & 3, swz = (srow & 7) << 4;
  int sd0 = srow * 128 + ((c4 * 32) ^ swz);
  int sd1 = srow * 128 + ((c4 * 32 + 16) ^ swz);
  const int kt0 = c * (qblk + 1), kt1 = kt0 + qblk + 1;

  // prologue: stage tile kt0
  {
    const u16* ksrc = kh + (size_t)(kt0 * 64 + srow) * HD + c4 * 16;
    const u16* vsrc = vh + (size_t)srow * SEQ + kt0 * 64 + c4 * 16;
    uint4 a0 = *(const uint4*)(ksrc), a1 = *(const uint4*)(ksrc + 8);
    uint4 b0 = *(const uint4*)(vsrc), b1 = *(const uint4*)(vsrc + 8);
    *(uint4*)((char*)Ks[0] + sd0) = a0; *(uint4*)((char*)Ks[0] + sd1) = a1;
    *(uint4*)((char*)Vs[0] + sd0) = b0; *(uint4*)((char*)Vs[0] + sd1) = b1;
  }
  __syncthreads();

  uint4 kr0, kr1, vr0, vr1;
  int lswz = (lq & 7) << 4;
  for (int kt = kt0; kt < kt1; kt++) {
    int b = (kt - kt0) & 1;
    if (kt + 1 < kt1) {
      const u16* ksrc = kh + (size_t)((kt + 1) * 64 + srow) * HD + c4 * 16;
      const u16* vsrc = vh + (size_t)srow * SEQ + (kt + 1) * 64 + c4 * 16;
      kr0 = *(const uint4*)(ksrc); kr1 = *(const uint4*)(ksrc + 8);
      vr0 = *(const uint4*)(vsrc); vr1 = *(const uint4*)(vsrc + 8);
    }

    if (kt * 64 <= wq0 + 31) {  // skip fully-masked tiles
      f32x16 sT[2] = {};
      const char* kbase = (const char*)Ks[b];
      __builtin_amdgcn_s_setprio(1);
#pragma unroll
      for (int t = 0; t < 2; t++) {
#pragma unroll
        for (int ds = 0; ds < 4; ds++) {
          bf16x8 kf = *(const bf16x8*)(kbase + (t * 32 + lq) * 128 +
                                       ((ds * 32 + hi * 16) ^ lswz));
          sT[t] = __builtin_amdgcn_mfma_f32_32x32x16_bf16(kf, qf[ds], sT[t], 0, 0, 0);
        }
      }
      __builtin_amdgcn_s_setprio(0);

      if (kt * 64 + 63 > wq0) {
#pragma unroll
        for (int t = 0; t < 2; t++)
#pragma unroll
          for (int r = 0; r < 16; r++) {
            int kg = kt * 64 + t * 32 + (r & 3) + 8 * (r >> 2) + 4 * hi;
            if (kg > qg) sT[t][r] = -__builtin_inff();
          }
      }

      float pmax = sT[0][0];
#pragma unroll
      for (int r = 1; r < 16; r++) pmax = fmaxf(pmax, sT[0][r]);
#pragma unroll
      for (int r = 0; r < 16; r++) pmax = fmaxf(pmax, sT[1][r]);
      pmax = fmaxf(pmax, __shfl_xor(pmax, 32, 64));

      if (!__all(pmax <= m_r + 8.f)) {
        float mn = fmaxf(m_r, pmax);
        float scl = __builtin_amdgcn_exp2f(m_r - mn);
        l_r *= scl;
        acc[0] *= scl;
        acc[1] *= scl;
        m_r = mn;
      }

      float ss = 0.f;
#pragma unroll
      for (int t = 0; t < 2; t++)
#pragma unroll
        for (int r = 0; r < 16; r++) {
          float p = __builtin_amdgcn_exp2f(sT[t][r] - m_r);
          sT[t][r] = p;
          ss += p;
        }
      ss += __shfl_xor(ss, 32, 64);
      l_r += ss;

      const char* vbase = (const char*)Vs[b];
#pragma unroll
      for (int t = 0; t < 2; t++) {
        unsigned cp[4][2];
#pragma unroll
        for (int m = 0; m < 4; m++) {
          cp[m][0] = pk2(sT[t][4 * m + 0], sT[t][4 * m + 1]);
          cp[m][1] = pk2(sT[t][4 * m + 2], sT[t][4 * m + 3]);
        }
#pragma unroll
        for (int kl = 0; kl < 2; kl++) {
          unsigned s0 = hi ? cp[2 * kl][0] : cp[2 * kl + 1][0];
          unsigned s1 = hi ? cp[2 * kl][1] : cp[2 * kl + 1][1];
          unsigned r0 = (unsigned)__shfl_xor((int)s0, 32, 64);
          unsigned r1 = (unsigned)__shfl_xor((int)s1, 32, 64);
          union { unsigned u[4]; bf16x8 v; } pa;
          pa.u[0] = hi ? r0 : cp[2 * kl][0];
          pa.u[1] = hi ? r1 : cp[2 * kl][1];
          pa.u[2] = hi ? cp[2 * kl + 1][0] : r0;
          pa.u[3] = hi ? cp[2 * kl + 1][1] : r1;
          int ks = t * 2 + kl;
          __builtin_amdgcn_s_setprio(1);
#pragma unroll
          for (int dt = 0; dt < 2; dt++) {
            bf16x8 vb = *(const bf16x8*)(vbase + (dt * 32 + lq) * 128 +
                                         ((ks * 32 + hi * 16) ^ lswz));
            acc[dt] = __builtin_amdgcn_mfma_f32_32x32x16_bf16(vb, pa.v, acc[dt], 0, 0, 0);
          }
          __builtin_amdgcn_s_setprio(0);
        }
      }
    }

    if (kt + 1 < kt1) {
      *(uint4*)((char*)Ks[b ^ 1] + sd0) = kr0;
      *(uint4*)((char*)Ks[b ^ 1] + sd1) = kr1;
      *(uint4*)((char*)Vs[b ^ 1] + sd0) = vr0;
      *(uint4*)((char*)Vs[b ^ 1] + sd1) = vr1;
    }
    __syncthreads();
  }

  // epilogue: dump raw-lane-layout partial O (bf16 pairs) + (m,l), coalesced
  unsigned* op = Opart + (size_t)c * OCH + ((size_t)(b5 * 4 + w) * 16) * 64;
#pragma unroll
  for (int dt = 0; dt < 2; dt++)
#pragma unroll
    for (int j = 0; j < 8; j++)
      op[(dt * 8 + j) * 64 + l] = pk2(acc[dt][2 * j], acc[dt][2 * j + 1]);
  if (!hi)
    ml[c * (HEADS * SEQ) + h * SEQ + wq0 + lq] = make_float2(m_r, l_r);
}

// ---------- Flash pass 2: merge chunk partials, transpose, write av ----------
__global__ __launch_bounds__(256) void k_merge(const unsigned* __restrict__ Opart,
                                               const float2* __restrict__ ml,
                                               u16* __restrict__ av) {
  __shared__ u16 Ts[8192];  // 16KB: 4 waves x 4KB transpose staging
  int bid = blockIdx.x;
  int h = bid & 31, qblk = bid >> 5;
  int b5 = ((SEQ / 128 - 1 - qblk) << 5) | h;  // pass-1 flat block index
  int tid = threadIdx.x, w = tid >> 6, l = tid & 63;
  int lq = l & 31, hi = l >> 5;
  int wq0 = qblk * 128 + w * 32;

  float2 ml0 = ml[h * SEQ + wq0 + lq];
  float2 ml1 = ml[HEADS * SEQ + h * SEQ + wq0 + lq];
  float m = fmaxf(ml0.x, ml1.x);
  float f0 = __builtin_amdgcn_exp2f(ml0.x - m);
  float f1 = __builtin_amdgcn_exp2f(ml1.x - m);
  float inv = 1.0f / (ml0.y * f0 + ml1.y * f1);

  const unsigned* op0 = Opart + ((size_t)(b5 * 4 + w) * 16) * 64;
  const unsigned* op1 = op0 + OCH;
  f32x16 acc[2];
#pragma unroll
  for (int dt = 0; dt < 2; dt++)
#pragma unroll
    for (int j = 0; j < 8; j++) {
      unsigned a0 = op0[(dt * 8 + j) * 64 + l];
      unsigned a1 = op1[(dt * 8 + j) * 64 + l];
      acc[dt][2 * j] = bflo(a0) * f0 + bflo(a1) * f1;
      acc[dt][2 * j + 1] = bfhi(a0) * f0 + bfhi(a1) * f1;
    }

  // LDS transpose epilogue (identical to R6 flash)
  int lswz = (lq & 7) << 4;
  char* wbase = (char*)Ts + w * 4096;
#pragma unroll
  for (int dt = 0; dt < 2; dt++)
#pragma unroll
    for (int m4 = 0; m4 < 4; m4++) {
      int r0 = 4 * m4;
      uint2 pr;
      pr.x = pk2(acc[dt][r0 + 0] * inv, acc[dt][r0 + 1] * inv);
      pr.y = pk2(acc[dt][r0 + 2] * inv, acc[dt][r0 + 3] * inv);
      int byte = lq * 128 + ((dt * 64 + m4 * 16 + hi * 8) ^ lswz);
      *(uint2*)(wbase + byte) = pr;
    }
  __syncthreads();
  int q2 = l >> 1, cH = l & 1;
  int qswz = (q2 & 7) << 4;
#pragma unroll
  for (int i = 0; i < 4; i++) {
    uint4 d = *(const uint4*)(wbase + q2 * 128 + ((cH * 64 + i * 16) ^ qswz));
    *(uint4*)(av + (size_t)(wq0 + q2) * HID + h * HD + cH * 32 + i * 8) = d;
  }
}

extern "C" void kernel_launch(void* const* d_in, const int* in_sizes, int n_in,
                              void* d_out, int out_size, void* d_ws, size_t ws_size,
                              hipStream_t stream) {
  (void)in_sizes; (void)n_in; (void)out_size; (void)ws_size;
  const float* x = (const float*)d_in[0];
  const float* cosp = (const float*)d_in[1];
  const float* sinp = (const float*)d_in[2];
  const float* Wq = (const float*)d_in[3];
  const float* Wk = (const float*)d_in[4];
  const float* Wv = (const float*)d_in[5];
  const float* Wo = (const float*)d_in[6];
  float* out = (float*)d_out;
  char* ws = (char*)d_ws;

  // workspace layout (64 MiB exactly):
  u16* xb = (u16*)(ws);                          // [0,8M)   x bf16; dead after qkv
  float2* mlb = (float2*)(ws);                   // [0,1M)   aliases dead xb (flash2+)
  u16* Wqkv = (u16*)(ws + ((size_t)8 << 20));    // [8,20M)  Wq^T|Wk^T|Wv^T
  u16* WoT = (u16*)(ws + ((size_t)20 << 20));    // [20,28M) Wo^T
  u16* qbuf = (u16*)(ws + ((size_t)28 << 20));   // [28,36M) q rope bf16 [32][S][64]
  u16* kbuf = (u16*)(ws + ((size_t)36 << 20));   // [36,38M) k rope bf16 [8][S][64]
  u16* vtb = (u16*)(ws + ((size_t)38 << 20));    // [38,40M) v^T bf16 [8][64][S]
  u16* av = (u16*)(ws + ((size_t)40 << 20));     // [40,48M) av bf16 [S][2048]
  unsigned* Opart = (unsigned*)(ws + ((size_t)48 << 20));  // [48,64M) 2 chunks x 8M

  k_f2b<<<(SEQ * HID / 4 + 255) / 256, 256, 0, stream>>>(x, xb, SEQ * HID / 4);
  k_tconv4<<<10240, 256, 0, stream>>>(Wq, Wk, Wv, Wo, Wqkv, WoT);
  k_gemm_qkv<<<256, 512, 0, stream>>>(xb, Wqkv, cosp, sinp, qbuf, kbuf, vtb);
  k_flash2<<<(SEQ / 128) * HEADS * 2, 256, 0, stream>>>(qbuf, kbuf, vtb, Opart, mlb);
  k_merge<<<(SEQ / 128) * HEADS, 256, 0, stream>>>(Opart, mlb, av);
  k_gemm<<<dim3(SEQ / 128, HID / 128), 256, 0, stream>>>(av, WoT, out, SEQ, HID, HID);
}

// Round 11
// 118.368 us; speedup vs baseline: 1.3839x; 1.0218x over previous
//
#include <hip/hip_runtime.h>

typedef unsigned short u16;
typedef __attribute__((ext_vector_type(4))) float f32x4;
typedef __attribute__((ext_vector_type(16))) float f32x16;
typedef __attribute__((ext_vector_type(8))) __bf16 bf16x8;
typedef __attribute__((ext_vector_type(2))) __bf16 bf16x2;

#define HEADS 32
#define KV_HEADS 8
#define HD 64
#define SEQ 2048
#define HID 2048
#define NQK 3072  // 2048 (Q) + 512 (K) + 512 (V)
#define QSCALE (0.125f * 1.4426950408889634f)  // exp2-domain softmax
#define OCH 2097152u  // u32s per partial-O chunk (512 blk * 4 waves * 16 * 64)

#define AS1 __attribute__((address_space(1)))
#define AS3 __attribute__((address_space(3)))

__device__ __forceinline__ u16 f2bf(float f) {
  unsigned u = __float_as_uint(f);
  u += 0x7FFFu + ((u >> 16) & 1u);
  return (u16)(u >> 16);
}

__device__ __forceinline__ unsigned pk2(float a, float b) {
  union { bf16x2 h; unsigned u; } c;
  c.h[0] = (__bf16)a; c.h[1] = (__bf16)b;
  return c.u;
}

__device__ __forceinline__ float bflo(unsigned u) {
  return __uint_as_float(u << 16);
}
__device__ __forceinline__ float bfhi(unsigned u) {
  return __uint_as_float(u & 0xFFFF0000u);
}

__device__ __forceinline__ void load16_to_lds(const void* g, void* l) {
  __builtin_amdgcn_global_load_lds((AS1 void*)(void*)g, (AS3 void*)l, 16, 0, 0);
}

// ---------- fp32 -> bf16 elementwise (4 elems/thread) ----------
__global__ __launch_bounds__(256) void k_f2b(const float* __restrict__ in,
                                             u16* __restrict__ out, int n4) {
  int i = blockIdx.x * 256 + threadIdx.x;
  if (i >= n4) return;
  float4 v = ((const float4*)in)[i];
  ushort4 o;
  o.x = f2bf(v.x); o.y = f2bf(v.y); o.z = f2bf(v.z); o.w = f2bf(v.w);
  ((ushort4*)out)[i] = o;
}

// ---------- fused transpose+convert for all 4 weight matrices (R10) --------
// out[c*ldo + r] = bf16(in[r*ldi + c]); flat grid, range-decoded segments:
// [0,4096) Wq  [4096,5120) Wk  [5120,6144) Wv  [6144,10240) Wo
__global__ __launch_bounds__(256) void k_tconv4(const float* __restrict__ Wq,
                                                const float* __restrict__ Wk,
                                                const float* __restrict__ Wv,
                                                const float* __restrict__ Wo,
                                                u16* __restrict__ Wqkv,
                                                u16* __restrict__ WoT) {
  __shared__ float tile[32][33];
  int bid = blockIdx.x;
  const float* in; u16* out; int ldi, cx, cy;
  if (bid < 4096) {
    in = Wq; out = Wqkv; ldi = 2048; cx = bid & 63; cy = bid >> 6;
  } else if (bid < 5120) {
    int b = bid - 4096;
    in = Wk; out = Wqkv + (size_t)2048 * 2048; ldi = 512; cx = b & 15; cy = b >> 4;
  } else if (bid < 6144) {
    int b = bid - 5120;
    in = Wv; out = Wqkv + (size_t)2560 * 2048; ldi = 512; cx = b & 15; cy = b >> 4;
  } else {
    int b = bid - 6144;
    in = Wo; out = WoT; ldi = 2048; cx = b & 63; cy = b >> 6;
  }
  const int ldo = 2048;
  int c0 = cx * 32, r0 = cy * 32;
  int col = threadIdx.x & 31, rw = threadIdx.x >> 5;
#pragma unroll
  for (int i = 0; i < 4; i++)
    tile[rw + i * 8][col] = in[(size_t)(r0 + rw + i * 8) * ldi + c0 + col];
  __syncthreads();
#pragma unroll
  for (int i = 0; i < 4; i++)
    out[(size_t)(c0 + rw + i * 8) * ldo + r0 + col] = f2bf(tile[col][rw + i * 8]);
}

// ======================= out-proj GEMM (R3 template, verbatim) ==============
// 128x128 block tile, BK=64, 4 waves each 64x64 quadrant, depth-2 counted
// vmcnt pipeline, 8-slot source-swizzle.  2D grid 16x16 (best-total config).

__device__ __forceinline__ void stage8(const u16* Ap, const u16* Bp, u16* AsX,
                                       u16* BsX, int tid, int K, int koff) {
#pragma unroll
  for (int i = 0; i < 4; i++) {
    load16_to_lds(Ap + (size_t)(i * 32) * K + koff, AsX + (i * 256 + tid) * 8);
    load16_to_lds(Bp + (size_t)(i * 32) * K + koff, BsX + (i * 256 + tid) * 8);
  }
}

__device__ __forceinline__ void frag16(const u16* Asb, const u16* Bsb,
                                       const int aoff[4][2], const int boff[4][2],
                                       f32x4 acc[4][4]) {
#pragma unroll
  for (int kk = 0; kk < 2; kk++) {
    bf16x8 a[4], b[4];
#pragma unroll
    for (int i = 0; i < 4; i++)
      a[i] = *(const bf16x8*)((const char*)Asb + aoff[i][kk]);
#pragma unroll
    for (int j = 0; j < 4; j++)
      b[j] = *(const bf16x8*)((const char*)Bsb + boff[j][kk]);
#pragma unroll
    for (int i = 0; i < 4; i++)
#pragma unroll
      for (int j = 0; j < 4; j++)
        acc[i][j] = __builtin_amdgcn_mfma_f32_16x16x32_bf16(a[i], b[j], acc[i][j], 0, 0, 0);
  }
}

#define TILE_STEP(AsX, BsX, tnext)                              \
  do {                                                          \
    asm volatile("s_waitcnt vmcnt(8)" ::: "memory");            \
    __builtin_amdgcn_sched_barrier(0);                          \
    __builtin_amdgcn_s_barrier();                               \
    frag16(AsX, BsX, aoff, boff, acc);                          \
    __builtin_amdgcn_sched_barrier(0);                          \
    __builtin_amdgcn_s_barrier();                               \
    stage8(Ap, Bp, AsX, BsX, tid, K, (tnext) * 64);             \
    __builtin_amdgcn_sched_barrier(0);                          \
  } while (0)

#define TILE_TAIL(AsX, BsX, n)                                  \
  do {                                                          \
    asm volatile("s_waitcnt vmcnt(" #n ")" ::: "memory");       \
    __builtin_amdgcn_sched_barrier(0);                          \
    __builtin_amdgcn_s_barrier();                               \
    frag16(AsX, BsX, aoff, boff, acc);                          \
  } while (0)

__global__ __launch_bounds__(256) void k_gemm(const u16* __restrict__ A,
                                              const u16* __restrict__ Bt,
                                              float* __restrict__ C,
                                              int M, int N, int K) {
  __shared__ u16 smem[32768];  // 64KB: 2 x (A 16KB + B 16KB)
  u16* As0 = smem;          u16* As1 = smem + 8192;
  u16* Bs0 = smem + 16384;  u16* Bs1 = smem + 24576;
  int tid = threadIdx.x;
  int m0 = blockIdx.x * 128, n0 = blockIdx.y * 128;
  int l = tid & 63, w = tid >> 6;
  int lr = l & 15, lg = l >> 4;
  int wr = (w >> 1) * 64, wc = (w & 1) * 64;
  f32x4 acc[4][4] = {};
  int r8 = tid >> 3;
  int sx = (tid & 7) ^ (r8 & 7);
  const u16* Ap = A + (size_t)(m0 + r8) * K + sx * 8;
  const u16* Bp = Bt + (size_t)(n0 + r8) * K + sx * 8;
  int aoff[4][2], boff[4][2];
#pragma unroll
  for (int i = 0; i < 4; i++) {
    int ra = wr + i * 16 + lr;
    int rb = wc + i * 16 + lr;
#pragma unroll
    for (int kk = 0; kk < 2; kk++) {
      aoff[i][kk] = ra * 128 + (((lg + kk * 4) ^ (ra & 7)) << 4);
      boff[i][kk] = rb * 128 + (((lg + kk * 4) ^ (rb & 7)) << 4);
    }
  }
  stage8(Ap, Bp, As0, Bs0, tid, K, 0);
  stage8(Ap, Bp, As1, Bs1, tid, K, 64);
#pragma unroll 1
  for (int t = 0; t < 30; t += 2) {
    TILE_STEP(As0, Bs0, t + 2);
    TILE_STEP(As1, Bs1, t + 3);
  }
  TILE_TAIL(As0, Bs0, 8);
  TILE_TAIL(As1, Bs1, 0);

#pragma unroll
  for (int i = 0; i < 4; i++)
#pragma unroll
    for (int j = 0; j < 4; j++)
#pragma unroll
      for (int r = 0; r < 4; r++)
        C[(size_t)(m0 + wr + i * 16 + lg * 4 + r) * N + n0 + wc + j * 16 + lr] =
            acc[i][j][r];
}

// ======================= QKV GEMM (R9 config, verbatim — best measured) =====
// 64x192 tile, grid 512 = 32x16 = exactly 2 blocks/CU (balanced makespan +
// 2-block TLP; measured 47.3us, MfmaUtil 21.2%).  Depth-2, global_load_lds,
// 8-slot source-swizzle, vmcnt(8).  Wave tile 32x96.  XCD swizzle: 512 =
// 8 x 64; each XCD owns 2 contiguous B-panels.  Per-16-col-fragment Q/K/V
// epilogue; V drain 2 passes (384 items on 256 threads).

__device__ __forceinline__ void stageQ(const u16* Ap, const u16* Bp, u16* S,
                                       int tid, int koff) {
#pragma unroll
  for (int i = 0; i < 2; i++)
    load16_to_lds(Ap + (size_t)(i * 32) * HID + koff, S + (i * 256 + tid) * 8);
#pragma unroll
  for (int i = 0; i < 6; i++)
    load16_to_lds(Bp + (size_t)(i * 32) * HID + koff, S + 4096 + (i * 256 + tid) * 8);
}

__device__ __forceinline__ void frag26(const u16* Sb, const int aoff[2][2],
                                       const int boff[6][2], f32x4 acc[2][6]) {
#pragma unroll
  for (int kk = 0; kk < 2; kk++) {
    bf16x8 a[2], b[6];
#pragma unroll
    for (int i = 0; i < 2; i++)
      a[i] = *(const bf16x8*)((const char*)Sb + aoff[i][kk]);
#pragma unroll
    for (int j = 0; j < 6; j++)
      b[j] = *(const bf16x8*)((const char*)Sb + 8192 + boff[j][kk]);
    __builtin_amdgcn_s_setprio(1);
#pragma unroll
    for (int i = 0; i < 2; i++)
#pragma unroll
      for (int j = 0; j < 6; j++)
        acc[i][j] = __builtin_amdgcn_mfma_f32_16x16x32_bf16(a[i], b[j], acc[i][j], 0, 0, 0);
    __builtin_amdgcn_s_setprio(0);
  }
}

#define QK_STEP(Sc, tnext)                                      \
  do {                                                          \
    asm volatile("s_waitcnt vmcnt(8)" ::: "memory");            \
    __builtin_amdgcn_sched_barrier(0);                          \
    __builtin_amdgcn_s_barrier();                               \
    frag26(Sc, aoff, boff, acc);                                \
    __builtin_amdgcn_sched_barrier(0);                          \
    __builtin_amdgcn_s_barrier();                               \
    stageQ(Ap, Bp, Sc, tid, (tnext) * 64);                      \
    __builtin_amdgcn_sched_barrier(0);                          \
  } while (0)

#define QK_TAIL(Sc, n)                                          \
  do {                                                          \
    asm volatile("s_waitcnt vmcnt(" #n ")" ::: "memory");       \
    __builtin_amdgcn_sched_barrier(0);                          \
    __builtin_amdgcn_s_barrier();                               \
    frag26(Sc, aoff, boff, acc);                                \
  } while (0)

__global__ __launch_bounds__(256) void k_gemm_qkv(const u16* __restrict__ A,
                                                  const u16* __restrict__ Bt,
                                                  const float* __restrict__ cosp,
                                                  const float* __restrict__ sinp,
                                                  u16* __restrict__ qbuf,
                                                  u16* __restrict__ kbuf,
                                                  u16* __restrict__ vtb) {
  __shared__ u16 smem[32768];  // 64KB: 2 sets x (A 8KB + B 24KB)
  u16* S0 = smem;              // set 0
  u16* S1 = smem + 16384;      // set 1
  u16* Ts = smem;              // 24KB: 192 cols x 64 rows x 2B (V epilogue)
  int tid = threadIdx.x;
  // XCD swizzle: grid 512 (32m x 16n); XCD (= bid%8 heuristic) owns 2 B-panels
  int bid = blockIdx.x;
  int wg = (bid & 7) * 64 + (bid >> 3);
  int m0 = (wg & 31) * 64, n0 = (wg >> 5) * 192;
  int l = tid & 63, w = tid >> 6;
  int lr = l & 15, lg = l >> 4;
  int wr = (w >> 1) * 32, wc = (w & 1) * 96;
  f32x4 acc[2][6] = {};
  int r8 = tid >> 3;
  int sx = (tid & 7) ^ (r8 & 7);
  const u16* Ap = A + (size_t)(m0 + r8) * HID + sx * 8;
  const u16* Bp = Bt + (size_t)(n0 + r8) * HID + sx * 8;
  int aoff[2][2], boff[6][2];
#pragma unroll
  for (int i = 0; i < 2; i++) {
    int ra = wr + i * 16 + lr;
#pragma unroll
    for (int kk = 0; kk < 2; kk++)
      aoff[i][kk] = ra * 128 + (((lg + kk * 4) ^ (ra & 7)) << 4);
  }
#pragma unroll
  for (int j = 0; j < 6; j++) {
    int rb = wc + j * 16 + lr;
#pragma unroll
    for (int kk = 0; kk < 2; kk++)
      boff[j][kk] = rb * 128 + (((lg + kk * 4) ^ (rb & 7)) << 4);
  }

  stageQ(Ap, Bp, S0, tid, 0);
  stageQ(Ap, Bp, S1, tid, 64);
#pragma unroll 1
  for (int t = 0; t < 30; t += 2) {
    QK_STEP(S0, t + 2);
    QK_STEP(S1, t + 3);
  }
  QK_TAIL(S0, 8);
  QK_TAIL(S1, 0);

  // ---- epilogue: per-fragment Q/K RoPE stores; V via Ts transpose ----
  int odd = lr & 1;
#pragma unroll
  for (int j = 0; j < 6; j++) {
    int colf = n0 + wc + j * 16;  // wave-uniform, multiple of 16
    if (colf < 2560) {
      bool isQ = colf < 2048;
      float scale = isQ ? QSCALE : 1.0f;
      u16* base = isQ ? qbuf + (size_t)(colf >> 6) * SEQ * HD
                      : kbuf + (size_t)((colf - 2048) >> 6) * SEQ * HD;
      int ch = colf & 63;              // col-in-head base (multiple of 16)
      int ii = (ch >> 1) + (lr >> 1);  // RoPE pair index within head
#pragma unroll
      for (int i = 0; i < 2; i++)
#pragma unroll
        for (int r = 0; r < 4; r++) {
          float v = acc[i][j][r];
          float vp = __shfl_xor(v, 1, 64);
          int sr = m0 + wr + i * 16 + lg * 4 + r;
          float cs = cosp[sr * 32 + ii], sn = sinp[sr * 32 + ii];
          float x1 = odd ? vp : v, x2 = odd ? v : vp;
          float o = odd ? (x1 * sn + x2 * cs) : (x1 * cs - x2 * sn);
          base[(size_t)sr * HD + ch + lr] = f2bf(o * scale);
        }
    }
  }
  if (n0 + 192 > 2560) {  // block contains V columns
    __syncthreads();      // all waves done with pipeline LDS
#pragma unroll
    for (int j = 0; j < 6; j++) {
      int colf = n0 + wc + j * 16;
      if (colf >= 2560) {
#pragma unroll
        for (int i = 0; i < 2; i++)
#pragma unroll
          for (int r = 0; r < 4; r++) {
            int cB = wc + j * 16 + lr, rB = wr + i * 16 + lg * 4 + r;
            *(u16*)((char*)Ts + cB * 128 + ((rB * 2) ^ ((cB & 7) << 4))) =
                f2bf(acc[i][j][r]);
          }
      }
    }
    __syncthreads();
    int half = tid & 1;
#pragma unroll
    for (int p = 0; p < 2; p++) {
      int c = p * 128 + (tid >> 1);
      if (c < 192 && n0 + c >= 2560) {
        int col = n0 + c;
        int kvh = (col - 2560) >> 6, d = col & 63;
        u16* dst = vtb + (size_t)kvh * HD * SEQ + (size_t)d * SEQ + m0 + half * 32;
        const char* src = (const char*)Ts + c * 128;
        int cs7 = (c & 7) << 4;
#pragma unroll
        for (int q = 0; q < 4; q++)
          *(uint4*)(dst + q * 8) = *(const uint4*)(src + ((half * 64 + q * 16) ^ cs7));
      }
    }
  }
}

// ---------- Flash attention pass 1: KV-split x2, partial O + (m,l) ----------
__global__ __launch_bounds__(256) void k_flash2(const u16* __restrict__ qb,
                                                const u16* __restrict__ kb,
                                                const u16* __restrict__ vt,
                                                unsigned* __restrict__ Opart,
                                                float2* __restrict__ ml) {
  __shared__ u16 Ks[2][64 * 64];
  __shared__ u16 Vs[2][64 * 64];
  int bid = blockIdx.x;
  int c = bid & 1;                  // chunk fastest
  int b5 = bid >> 1;                // 0..511
  int h = b5 & 31;                  // heads next
  int qi = b5 >> 5;
  int qblk = (SEQ / 128) - 1 - qi;  // LPT: heaviest first
  int kvh = h & 7;
  int tid = threadIdx.x, w = tid >> 6, l = tid & 63;
  int lq = l & 31, hi = l >> 5;
  const u16* qh = qb + (size_t)h * SEQ * HD;
  const u16* kh = kb + (size_t)kvh * SEQ * HD;
  const u16* vh = vt + (size_t)kvh * HD * SEQ;
  int wq0 = qblk * 128 + w * 32;
  int qg = wq0 + lq;

  bf16x8 qf[4];
#pragma unroll
  for (int ds = 0; ds < 4; ds++)
    qf[ds] = *(const bf16x8*)(qh + (size_t)qg * HD + ds * 16 + hi * 8);

  f32x16 acc[2] = {};   // O^T: lane: q=l&31, d = dt*32 + (r&3)+8*(r>>2)+4*hi
  float m_r = -__builtin_inff(), l_r = 0.f;

  int srow = tid >> 2, c4 = tid & 3, swz = (srow & 7) << 4;
  int sd0 = srow * 128 + ((c4 * 32) ^ swz);
  int sd1 = srow * 128 + ((c4 * 32 + 16) ^ swz);
  const int kt0 = c * (qblk + 1), kt1 = kt0 + qblk + 1;

  // prologue: stage tile kt0
  {
    const u16* ksrc = kh + (size_t)(kt0 * 64 + srow) * HD + c4 * 16;
    const u16* vsrc = vh + (size_t)srow * SEQ + kt0 * 64 + c4 * 16;
    uint4 a0 = *(const uint4*)(ksrc), a1 = *(const uint4*)(ksrc + 8);
    uint4 b0 = *(const uint4*)(vsrc), b1 = *(const uint4*)(vsrc + 8);
    *(uint4*)((char*)Ks[0] + sd0) = a0; *(uint4*)((char*)Ks[0] + sd1) = a1;
    *(uint4*)((char*)Vs[0] + sd0) = b0; *(uint4*)((char*)Vs[0] + sd1) = b1;
  }
  __syncthreads();

  uint4 kr0, kr1, vr0, vr1;
  int lswz = (lq & 7) << 4;
  for (int kt = kt0; kt < kt1; kt++) {
    int b = (kt - kt0) & 1;
    if (kt + 1 < kt1) {
      const u16* ksrc = kh + (size_t)((kt + 1) * 64 + srow) * HD + c4 * 16;
      const u16* vsrc = vh + (size_t)srow * SEQ + (kt + 1) * 64 + c4 * 16;
      kr0 = *(const uint4*)(ksrc); kr1 = *(const uint4*)(ksrc + 8);
      vr0 = *(const uint4*)(vsrc); vr1 = *(const uint4*)(vsrc + 8);
    }

    if (kt * 64 <= wq0 + 31) {  // skip fully-masked tiles
      f32x16 sT[2] = {};
      const char* kbase = (const char*)Ks[b];
      __builtin_amdgcn_s_setprio(1);
#pragma unroll
      for (int t = 0; t < 2; t++) {
#pragma unroll
        for (int ds = 0; ds < 4; ds++) {
          bf16x8 kf = *(const bf16x8*)(kbase + (t * 32 + lq) * 128 +
                                       ((ds * 32 + hi * 16) ^ lswz));
          sT[t] = __builtin_amdgcn_mfma_f32_32x32x16_bf16(kf, qf[ds], sT[t], 0, 0, 0);
        }
      }
      __builtin_amdgcn_s_setprio(0);

      if (kt * 64 + 63 > wq0) {
#pragma unroll
        for (int t = 0; t < 2; t++)
#pragma unroll
          for (int r = 0; r < 16; r++) {
            int kg = kt * 64 + t * 32 + (r & 3) + 8 * (r >> 2) + 4 * hi;
            if (kg > qg) sT[t][r] = -__builtin_inff();
          }
      }

      float pmax = sT[0][0];
#pragma unroll
      for (int r = 1; r < 16; r++) pmax = fmaxf(pmax, sT[0][r]);
#pragma unroll
      for (int r = 0; r < 16; r++) pmax = fmaxf(pmax, sT[1][r]);
      pmax = fmaxf(pmax, __shfl_xor(pmax, 32, 64));

      if (!__all(pmax <= m_r + 8.f)) {
        float mn = fmaxf(m_r, pmax);
        float scl = __builtin_amdgcn_exp2f(m_r - mn);
        l_r *= scl;
        acc[0] *= scl;
        acc[1] *= scl;
        m_r = mn;
      }

      float ss = 0.f;
#pragma unroll
      for (int t = 0; t < 2; t++)
#pragma unroll
        for (int r = 0; r < 16; r++) {
          float p = __builtin_amdgcn_exp2f(sT[t][r] - m_r);
          sT[t][r] = p;
          ss += p;
        }
      ss += __shfl_xor(ss, 32, 64);
      l_r += ss;

      const char* vbase = (const char*)Vs[b];
#pragma unroll
      for (int t = 0; t < 2; t++) {
        unsigned cp[4][2];
#pragma unroll
        for (int m = 0; m < 4; m++) {
          cp[m][0] = pk2(sT[t][4 * m + 0], sT[t][4 * m + 1]);
          cp[m][1] = pk2(sT[t][4 * m + 2], sT[t][4 * m + 3]);
        }
#pragma unroll
        for (int kl = 0; kl < 2; kl++) {
          unsigned s0 = hi ? cp[2 * kl][0] : cp[2 * kl + 1][0];
          unsigned s1 = hi ? cp[2 * kl][1] : cp[2 * kl + 1][1];
          unsigned r0 = (unsigned)__shfl_xor((int)s0, 32, 64);
          unsigned r1 = (unsigned)__shfl_xor((int)s1, 32, 64);
          union { unsigned u[4]; bf16x8 v; } pa;
          pa.u[0] = hi ? r0 : cp[2 * kl][0];
          pa.u[1] = hi ? r1 : cp[2 * kl][1];
          pa.u[2] = hi ? cp[2 * kl + 1][0] : r0;
          pa.u[3] = hi ? cp[2 * kl + 1][1] : r1;
          int ks = t * 2 + kl;
          __builtin_amdgcn_s_setprio(1);
#pragma unroll
          for (int dt = 0; dt < 2; dt++) {
            bf16x8 vb = *(const bf16x8*)(vbase + (dt * 32 + lq) * 128 +
                                         ((ks * 32 + hi * 16) ^ lswz));
            acc[dt] = __builtin_amdgcn_mfma_f32_32x32x16_bf16(vb, pa.v, acc[dt], 0, 0, 0);
          }
          __builtin_amdgcn_s_setprio(0);
        }
      }
    }

    if (kt + 1 < kt1) {
      *(uint4*)((char*)Ks[b ^ 1] + sd0) = kr0;
      *(uint4*)((char*)Ks[b ^ 1] + sd1) = kr1;
      *(uint4*)((char*)Vs[b ^ 1] + sd0) = vr0;
      *(uint4*)((char*)Vs[b ^ 1] + sd1) = vr1;
    }
    __syncthreads();
  }

  // epilogue: dump raw-lane-layout partial O (bf16 pairs) + (m,l), coalesced
  unsigned* op = Opart + (size_t)c * OCH + ((size_t)(b5 * 4 + w) * 16) * 64;
#pragma unroll
  for (int dt = 0; dt < 2; dt++)
#pragma unroll
    for (int j = 0; j < 8; j++)
      op[(dt * 8 + j) * 64 + l] = pk2(acc[dt][2 * j], acc[dt][2 * j + 1]);
  if (!hi)
    ml[c * (HEADS * SEQ) + h * SEQ + wq0 + lq] = make_float2(m_r, l_r);
}

// ---------- Flash pass 2: merge chunk partials, transpose, write av ----------
__global__ __launch_bounds__(256) void k_merge(const unsigned* __restrict__ Opart,
                                               const float2* __restrict__ ml,
                                               u16* __restrict__ av) {
  __shared__ u16 Ts[8192];  // 16KB: 4 waves x 4KB transpose staging
  int bid = blockIdx.x;
  int h = bid & 31, qblk = bid >> 5;
  int b5 = ((SEQ / 128 - 1 - qblk) << 5) | h;  // pass-1 flat block index
  int tid = threadIdx.x, w = tid >> 6, l = tid & 63;
  int lq = l & 31, hi = l >> 5;
  int wq0 = qblk * 128 + w * 32;

  float2 ml0 = ml[h * SEQ + wq0 + lq];
  float2 ml1 = ml[HEADS * SEQ + h * SEQ + wq0 + lq];
  float m = fmaxf(ml0.x, ml1.x);
  float f0 = __builtin_amdgcn_exp2f(ml0.x - m);
  float f1 = __builtin_amdgcn_exp2f(ml1.x - m);
  float inv = 1.0f / (ml0.y * f0 + ml1.y * f1);

  const unsigned* op0 = Opart + ((size_t)(b5 * 4 + w) * 16) * 64;
  const unsigned* op1 = op0 + OCH;
  f32x16 acc[2];
#pragma unroll
  for (int dt = 0; dt < 2; dt++)
#pragma unroll
    for (int j = 0; j < 8; j++) {
      unsigned a0 = op0[(dt * 8 + j) * 64 + l];
      unsigned a1 = op1[(dt * 8 + j) * 64 + l];
      acc[dt][2 * j] = bflo(a0) * f0 + bflo(a1) * f1;
      acc[dt][2 * j + 1] = bfhi(a0) * f0 + bfhi(a1) * f1;
    }

  // LDS transpose epilogue (identical to R6 flash)
  int lswz = (lq & 7) << 4;
  char* wbase = (char*)Ts + w * 4096;
#pragma unroll
  for (int dt = 0; dt < 2; dt++)
#pragma unroll
    for (int m4 = 0; m4 < 4; m4++) {
      int r0 = 4 * m4;
      uint2 pr;
      pr.x = pk2(acc[dt][r0 + 0] * inv, acc[dt][r0 + 1] * inv);
      pr.y = pk2(acc[dt][r0 + 2] * inv, acc[dt][r0 + 3] * inv);
      int byte = lq * 128 + ((dt * 64 + m4 * 16 + hi * 8) ^ lswz);
      *(uint2*)(wbase + byte) = pr;
    }
  __syncthreads();
  int q2 = l >> 1, cH = l & 1;
  int qswz = (q2 & 7) << 4;
#pragma unroll
  for (int i = 0; i < 4; i++) {
    uint4 d = *(const uint4*)(wbase + q2 * 128 + ((cH * 64 + i * 16) ^ qswz));
    *(uint4*)(av + (size_t)(wq0 + q2) * HID + h * HD + cH * 32 + i * 8) = d;
  }
}

extern "C" void kernel_launch(void* const* d_in, const int* in_sizes, int n_in,
                              void* d_out, int out_size, void* d_ws, size_t ws_size,
                              hipStream_t stream) {
  (void)in_sizes; (void)n_in; (void)out_size; (void)ws_size;
  const float* x = (const float*)d_in[0];
  const float* cosp = (const float*)d_in[1];
  const float* sinp = (const float*)d_in[2];
  const float* Wq = (const float*)d_in[3];
  const float* Wk = (const float*)d_in[4];
  const float* Wv = (const float*)d_in[5];
  const float* Wo = (const float*)d_in[6];
  float* out = (float*)d_out;
  char* ws = (char*)d_ws;

  // workspace layout (64 MiB exactly):
  u16* xb = (u16*)(ws);                          // [0,8M)   x bf16; dead after qkv
  float2* mlb = (float2*)(ws);                   // [0,1M)   aliases dead xb (flash2+)
  u16* Wqkv = (u16*)(ws + ((size_t)8 << 20));    // [8,20M)  Wq^T|Wk^T|Wv^T
  u16* WoT = (u16*)(ws + ((size_t)20 << 20));    // [20,28M) Wo^T
  u16* qbuf = (u16*)(ws + ((size_t)28 << 20));   // [28,36M) q rope bf16 [32][S][64]
  u16* kbuf = (u16*)(ws + ((size_t)36 << 20));   // [36,38M) k rope bf16 [8][S][64]
  u16* vtb = (u16*)(ws + ((size_t)38 << 20));    // [38,40M) v^T bf16 [8][64][S]
  u16* av = (u16*)(ws + ((size_t)40 << 20));     // [40,48M) av bf16 [S][2048]
  unsigned* Opart = (unsigned*)(ws + ((size_t)48 << 20));  // [48,64M) 2 chunks x 8M

  k_f2b<<<(SEQ * HID / 4 + 255) / 256, 256, 0, stream>>>(x, xb, SEQ * HID / 4);
  k_tconv4<<<10240, 256, 0, stream>>>(Wq, Wk, Wv, Wo, Wqkv, WoT);
  k_gemm_qkv<<<512, 256, 0, stream>>>(xb, Wqkv, cosp, sinp, qbuf, kbuf, vtb);
  k_flash2<<<(SEQ / 128) * HEADS * 2, 256, 0, stream>>>(qbuf, kbuf, vtb, Opart, mlb);
  k_merge<<<(SEQ / 128) * HEADS, 256, 0, stream>>>(Opart, mlb, av);
  k_gemm<<<dim3(SEQ / 128, HID / 128), 256, 0, stream>>>(av, WoT, out, SEQ, HID, HID);
}